// Round 8
// baseline (300.857 us; speedup 1.0000x reference)
//
#include <hip/hip_runtime.h>
#include <hip/hip_bf16.h>
#include <math.h>

// ---------------------------------------------------------------------------
// TCCL model forward. Round 7:
//  - stage 1 conv -> MFMA (K=17 padded to 32); both stage-1 passes now ~free
//  - all conv stages: MODE0 stats-only pass (no y store) + MODE1/2/3 apply
//    pass (recompute conv + BN+ReLU(+pool/adapool) fused into epilogue)
//    -> bn_pool_t / bn_apply_t / bn_adapool_t kernels and ~200MB of
//       materialized-y HBM traffic removed
//  - maxpool4 across w done with 2 cross-lane shfl_xor maxes (w = lane&15)
// ---------------------------------------------------------------------------

#define BSZ2 512          // combined batch (x1 ++ x2)
#define NTHR 256

typedef __attribute__((ext_vector_type(8))) short bf16x8;
typedef __attribute__((ext_vector_type(4))) float f32x4;

static inline int ceil_divll(long long a, int b) { return (int)((a + b - 1) / b); }

__device__ __forceinline__ unsigned short f2bf(float f) {
    unsigned u = __float_as_uint(f);
    u = (u + 0x7FFFu + ((u >> 16) & 1u)) >> 16;
    return (unsigned short)u;
}
__device__ __forceinline__ float bf2f(unsigned short h) {
    return __uint_as_float(((unsigned)h) << 16);
}
__device__ __forceinline__ float bflo(unsigned u) { return __uint_as_float(u << 16); }
__device__ __forceinline__ float bfhi(unsigned u) { return __uint_as_float(u & 0xFFFF0000u); }

// ---------------- stage 1 MFMA conv (Cin=1, K=17 padded to 32) --------------
// MODE 0 = stats partials; MODE 1 = BN+ReLU+maxpool4 -> bf16 [b][wp][16]
template<int WT, int MODE>
__global__ __launch_bounds__(256)
void conv1_mfma(const float* __restrict__ x1, const float* __restrict__ x2,
                const unsigned short* __restrict__ wpack1, const float* __restrict__ bias,
                const float* __restrict__ scale, const float* __restrict__ shift,
                unsigned short* __restrict__ out, float* __restrict__ partials)
{
    constexpr int W = 8192;
    constexpr int CHUNK = 4 * WT * 16;
    __shared__ float xs[CHUNK + 32];
    __shared__ float sred[(MODE == 0) ? 4 : 1][4][4];
    __shared__ float ssred[(MODE == 0) ? 4 : 1][4][4];

    const int tid = threadIdx.x;
    const int ntile = W / CHUNK;
    const int b = blockIdx.x / ntile;
    const int w0 = (blockIdx.x % ntile) * CHUNK;
    const float* xrow = (b < 256) ? x1 + (long long)b * W : x2 + (long long)(b - 256) * W;

    for (int i = tid; i < CHUNK + 32; i += 256) {
        const int gw = w0 - 8 + i;
        xs[i] = (gw >= 0 && gw < W) ? xrow[gw] : 0.f;
    }
    __syncthreads();

    const int lane = tid & 63, wave = tid >> 6;
    const int n = lane & 15, kq = lane >> 4;
    const bf16x8 a = *(const bf16x8*)(wpack1 + lane * 8);

    f32x4 acc[WT];
#pragma unroll
    for (int wt = 0; wt < WT; ++wt) { acc[wt][0]=0.f; acc[wt][1]=0.f; acc[wt][2]=0.f; acc[wt][3]=0.f; }

    const int base0 = wave * WT * 16 + n + kq * 8;
#pragma unroll
    for (int wt = 0; wt < WT; ++wt) {
        bf16x8 bv;
#pragma unroll
        for (int j = 0; j < 8; ++j) {
            __hip_bfloat16 h = __float2bfloat16(xs[base0 + wt * 16 + j]);
            bv[j] = *reinterpret_cast<short*>(&h);
        }
        acc[wt] = __builtin_amdgcn_mfma_f32_16x16x32_bf16(a, bv, acc[wt], 0, 0, 0);
    }

    if (MODE == 0) {
        float bi[4];
#pragma unroll
        for (int e = 0; e < 4; ++e) bi[e] = bias[kq * 4 + e];
        float s_[4], ss_[4];
#pragma unroll
        for (int e = 0; e < 4; ++e) { s_[e] = 0.f; ss_[e] = 0.f; }
#pragma unroll
        for (int wt = 0; wt < WT; ++wt)
#pragma unroll
            for (int e = 0; e < 4; ++e) {
                const float y = acc[wt][e] + bi[e];
                s_[e] += y; ss_[e] += y * y;
            }
#pragma unroll
        for (int m = 1; m < 16; m <<= 1) {
#pragma unroll
            for (int e = 0; e < 4; ++e) {
                s_[e]  += __shfl_xor(s_[e], m, 64);
                ss_[e] += __shfl_xor(ss_[e], m, 64);
            }
        }
        if (n == 0) {
#pragma unroll
            for (int e = 0; e < 4; ++e) { sred[wave][kq][e] = s_[e]; ssred[wave][kq][e] = ss_[e]; }
        }
        __syncthreads();
        if (tid < 16) {
            const int q = tid >> 2, e = tid & 3;
            float sumv = 0.f, sumsq = 0.f;
#pragma unroll
            for (int wv = 0; wv < 4; ++wv) { sumv += sred[wv][q][e]; sumsq += ssred[wv][q][e]; }
            partials[((long long)blockIdx.x * 16 + tid) * 2 + 0] = sumv;
            partials[((long long)blockIdx.x * 16 + tid) * 2 + 1] = sumsq;
        }
    } else {
        const int half = b >> 8;
        float bi[4], scv[4], shv[4];
#pragma unroll
        for (int e = 0; e < 4; ++e) {
            bi[e]  = bias[kq * 4 + e];
            scv[e] = scale[half * 16 + kq * 4 + e];
            shv[e] = shift[half * 16 + kq * 4 + e];
        }
#pragma unroll
        for (int wt = 0; wt < WT; ++wt) {
            float v[4];
#pragma unroll
            for (int e = 0; e < 4; ++e) {
                v[e] = fmaf(scv[e], acc[wt][e] + bi[e], shv[e]);
                v[e] = fmaxf(v[e], __shfl_xor(v[e], 1, 64));
                v[e] = fmaxf(v[e], __shfl_xor(v[e], 2, 64));
                v[e] = fmaxf(v[e], 0.f);
            }
            if ((n & 3) == 0) {
                const int wp = (w0 + wave * WT * 16 + wt * 16 + n) >> 2;
                uint2 pk;
                pk.x = (unsigned)f2bf(v[0]) | ((unsigned)f2bf(v[1]) << 16);
                pk.y = (unsigned)f2bf(v[2]) | ((unsigned)f2bf(v[3]) << 16);
                *(uint2*)(out + ((long long)b * 2048 + wp) * 16 + kq * 4) = pk;
            }
        }
    }
}

// per-channel, per-half finalize. grid (COUT, 2).
template<int COUT>
__global__ void finalize2(const float* __restrict__ partials, int nblk_half, float invN,
                          const float* __restrict__ g, const float* __restrict__ be,
                          float* __restrict__ scale, float* __restrict__ shift)
{
    const int co = blockIdx.x;
    const int half = blockIdx.y;
    const float* P = partials + (size_t)half * nblk_half * COUT * 2;
    float s = 0.f, ss = 0.f;
    for (int i = threadIdx.x; i < nblk_half; i += NTHR) {
        s  += P[((long long)i * COUT + co) * 2 + 0];
        ss += P[((long long)i * COUT + co) * 2 + 1];
    }
    __shared__ float red[NTHR][2];
    red[threadIdx.x][0] = s; red[threadIdx.x][1] = ss;
    __syncthreads();
    for (int off = NTHR / 2; off > 0; off >>= 1) {
        if ((int)threadIdx.x < off) {
            red[threadIdx.x][0] += red[threadIdx.x + off][0];
            red[threadIdx.x][1] += red[threadIdx.x + off][1];
        }
        __syncthreads();
    }
    if (threadIdx.x == 0) {
        const float m = red[0][0] * invN;
        const float v = red[0][1] * invN - m * m;
        const float inv = rsqrtf(v + 1e-5f);
        const float sc = g[co] * inv;
        scale[half * COUT + co] = sc;
        shift[half * COUT + co] = be[co] - sc * m;
    }
}

// ---------------- weight prepacks (one launch) ------------------------------
template<int CIN, int KK, int DT, int NP, int S, int CT>
__device__ __forceinline__ void pack_one(int idx, const float* __restrict__ wgt,
                                         unsigned short* __restrict__ wp)
{
    const int j = idx & 7;
    const int l = (idx >> 3) & 63;
    int rest = idx >> 9;
    const int ct = rest % CT; rest /= CT;
    const int s = rest % S;
    const int p = rest / S;
    const int co = ct * 16 + (l & 15);
    const int k = (l >> 4) * 8 + j;
    int ci, t;
    if (DT == 2) { ci = k & (CIN - 1); t = p * 2 + (k >> 4); }
    else         { ci = s * 32 + k;    t = p; }
    float v = (t < KK) ? wgt[((long long)co * CIN + ci) * KK + t] : 0.f;
    wp[idx] = f2bf(v);
}

__global__ void build_all_wpacks(const float* __restrict__ w1, const float* __restrict__ w2,
                                 const float* __restrict__ w3,
                                 const float* __restrict__ tw1, const float* __restrict__ tw2,
                                 unsigned short* __restrict__ wp1,
                                 unsigned short* __restrict__ wp2, unsigned short* __restrict__ wp3,
                                 unsigned short* __restrict__ wpt1, unsigned short* __restrict__ wpt2)
{
    const int idx = blockIdx.x * NTHR + threadIdx.x;
    const int n1 = 512;
    const int n2 = 9 * 1 * 2 * 512;       // 9216
    const int n3 = 17 * 1 * 4 * 512;      // 34816
    const int nt1 = 5 * 2 * 4 * 512;      // 20480
    const int nt2 = 3 * 2 * 4 * 512;      // 12288
    if (idx < n1) {
        // stage-1 pack: co = l&15, k = (l>>4)*8 + j, t = k (pad k>=17 -> 0)
        const int j = idx & 7, l = idx >> 3;
        const int co = l & 15, k = (l >> 4) * 8 + j;
        wp1[idx] = f2bf((k < 17) ? w1[co * 17 + k] : 0.f);
    }
    else if (idx < n1 + n2) pack_one<16, 17, 2, 9, 1, 2>(idx - n1, w2, wp2);
    else if (idx < n1 + n2 + n3) pack_one<32, 17, 1, 17, 1, 4>(idx - n1 - n2, w3, wp3);
    else if (idx < n1 + n2 + n3 + nt1) pack_one<64, 5, 1, 5, 2, 4>(idx - n1 - n2 - n3, tw1, wpt1);
    else if (idx < n1 + n2 + n3 + nt1 + nt2) pack_one<64, 3, 1, 3, 2, 4>(idx - n1 - n2 - n3 - nt1, tw2, wpt2);
}

// ---------------- MFMA conv, multi-mode -------------------------------------
// MODE 0 = stats only; 1 = BN+ReLU+maxpool4 -> [b][W/4][COUT];
// MODE 2 = BN+ReLU -> [b][W][COUT]; 3 = BN+ReLU+adapool5 -> kk (block per b)
template<int CIN, int COUT, int KK, int PAD, int DT, int NP, int S, int CT, int ST, int MODE>
__global__ __launch_bounds__(256)
void conv_mfma(const unsigned short* __restrict__ xT, const unsigned short* __restrict__ wpack,
               const float* __restrict__ bias, const float* __restrict__ scale,
               const float* __restrict__ shift, unsigned short* __restrict__ out,
               float* __restrict__ kk, float* __restrict__ partials, int W)
{
    constexpr int CHUNK = 4 * ST * 16;
    constexpr int ROWB = CIN * 2 + 16;
    constexpr int ROWS = CHUNK + KK + (DT - 1) + 1;
    constexpr int DPR = CIN / 2;
    __shared__ __align__(16) unsigned char lx[ROWS * ROWB];
    __shared__ float sred[(MODE == 0) ? 4 : 1][CT][4][4];
    __shared__ float ssred[(MODE == 0) ? 4 : 1][CT][4][4];
    __shared__ float hb[(MODE == 3) ? 128 : 1][(MODE == 3) ? 68 : 1];

    const int tid = threadIdx.x;
    const int ntile = W / CHUNK;
    const int b = blockIdx.x / ntile;
    const int tile = blockIdx.x % ntile;
    const int w0 = tile * CHUNK;

    for (int d = tid; d < ROWS * DPR; d += 256) {
        const int row = d / DPR;
        const int col = d % DPR;
        const int gw = w0 - PAD + row;
        unsigned v = 0;
        if (gw >= 0 && gw < W)
            v = *(const unsigned*)(xT + (((long long)b * W + gw) * CIN + col * 2));
        *(unsigned*)(lx + row * ROWB + col * 4) = v;
    }
    __syncthreads();

    const int lane = tid & 63, wave = tid >> 6;
    const int n = lane & 15, kq = lane >> 4;
    int rowbase, cbyte;
    if (DT == 2) { rowbase = wave * ST * 16 + n + (kq >> 1); cbyte = (kq & 1) * 16; }
    else         { rowbase = wave * ST * 16 + n;             cbyte = kq * 16; }

    f32x4 acc[ST][CT];
#pragma unroll
    for (int st = 0; st < ST; ++st)
#pragma unroll
        for (int ct = 0; ct < CT; ++ct) { acc[st][ct][0]=0.f; acc[st][ct][1]=0.f; acc[st][ct][2]=0.f; acc[st][ct][3]=0.f; }

#pragma unroll
    for (int p = 0; p < NP; ++p) {
#pragma unroll
        for (int s = 0; s < S; ++s) {
            bf16x8 a[CT];
#pragma unroll
            for (int ct = 0; ct < CT; ++ct)
                a[ct] = *(const bf16x8*)(wpack + (((long long)(p * S + s) * CT + ct) * 64 + lane) * 8);
#pragma unroll
            for (int st = 0; st < ST; ++st) {
                const int r = rowbase + st * 16 + p * DT;
                const bf16x8 bf = *(const bf16x8*)(lx + r * ROWB + cbyte + s * 64);
#pragma unroll
                for (int ct = 0; ct < CT; ++ct)
                    acc[st][ct] = __builtin_amdgcn_mfma_f32_16x16x32_bf16(a[ct], bf, acc[st][ct], 0, 0, 0);
            }
        }
    }

    if (MODE == 0) {
        float s_[CT][4], ss_[CT][4];
#pragma unroll
        for (int ct = 0; ct < CT; ++ct)
#pragma unroll
            for (int e = 0; e < 4; ++e) { s_[ct][e] = 0.f; ss_[ct][e] = 0.f; }
#pragma unroll
        for (int st = 0; st < ST; ++st)
#pragma unroll
            for (int ct = 0; ct < CT; ++ct) {
                const float* bp = bias + ct * 16 + kq * 4;
#pragma unroll
                for (int e = 0; e < 4; ++e) {
                    const float y = acc[st][ct][e] + bp[e];
                    s_[ct][e] += y; ss_[ct][e] += y * y;
                }
            }
#pragma unroll
        for (int m = 1; m < 16; m <<= 1) {
#pragma unroll
            for (int ct = 0; ct < CT; ++ct)
#pragma unroll
                for (int e = 0; e < 4; ++e) {
                    s_[ct][e]  += __shfl_xor(s_[ct][e], m, 64);
                    ss_[ct][e] += __shfl_xor(ss_[ct][e], m, 64);
                }
        }
        if (n == 0) {
#pragma unroll
            for (int ct = 0; ct < CT; ++ct)
#pragma unroll
                for (int e = 0; e < 4; ++e) {
                    sred[wave][ct][kq][e] = s_[ct][e];
                    ssred[wave][ct][kq][e] = ss_[ct][e];
                }
        }
        __syncthreads();
        if (tid < COUT) {
            const int ct = tid >> 4, q = (tid >> 2) & 3, e = tid & 3;
            float sumv = 0.f, sumsq = 0.f;
#pragma unroll
            for (int wv = 0; wv < 4; ++wv) { sumv += sred[wv][ct][q][e]; sumsq += ssred[wv][ct][q][e]; }
            partials[((long long)blockIdx.x * COUT + tid) * 2 + 0] = sumv;
            partials[((long long)blockIdx.x * COUT + tid) * 2 + 1] = sumsq;
        }
    } else {
        const int half = b >> 8;
        float bi[CT][4], scv[CT][4], shv[CT][4];
#pragma unroll
        for (int ct = 0; ct < CT; ++ct)
#pragma unroll
            for (int e = 0; e < 4; ++e) {
                const int co = ct * 16 + kq * 4 + e;
                bi[ct][e]  = bias[co];
                scv[ct][e] = scale[half * COUT + co];
                shv[ct][e] = shift[half * COUT + co];
            }
        if (MODE == 1) {
#pragma unroll
            for (int st = 0; st < ST; ++st) {
#pragma unroll
                for (int ct = 0; ct < CT; ++ct) {
                    float v[4];
#pragma unroll
                    for (int e = 0; e < 4; ++e) {
                        v[e] = fmaf(scv[ct][e], acc[st][ct][e] + bi[ct][e], shv[ct][e]);
                        v[e] = fmaxf(v[e], __shfl_xor(v[e], 1, 64));
                        v[e] = fmaxf(v[e], __shfl_xor(v[e], 2, 64));
                        v[e] = fmaxf(v[e], 0.f);
                    }
                    if ((n & 3) == 0) {
                        const int wp = (w0 + wave * ST * 16 + st * 16 + n) >> 2;
                        uint2 pk;
                        pk.x = (unsigned)f2bf(v[0]) | ((unsigned)f2bf(v[1]) << 16);
                        pk.y = (unsigned)f2bf(v[2]) | ((unsigned)f2bf(v[3]) << 16);
                        *(uint2*)(out + ((long long)b * (W >> 2) + wp) * COUT + ct * 16 + kq * 4) = pk;
                    }
                }
            }
        } else if (MODE == 2) {
#pragma unroll
            for (int st = 0; st < ST; ++st) {
                const int w = w0 + wave * ST * 16 + st * 16 + n;
                unsigned short* orow = out + ((long long)b * W + w) * COUT;
#pragma unroll
                for (int ct = 0; ct < CT; ++ct) {
                    float v[4];
#pragma unroll
                    for (int e = 0; e < 4; ++e)
                        v[e] = fmaxf(fmaf(scv[ct][e], acc[st][ct][e] + bi[ct][e], shv[ct][e]), 0.f);
                    uint2 pk;
                    pk.x = (unsigned)f2bf(v[0]) | ((unsigned)f2bf(v[1]) << 16);
                    pk.y = (unsigned)f2bf(v[2]) | ((unsigned)f2bf(v[3]) << 16);
                    *(uint2*)(orow + ct * 16 + kq * 4) = pk;
                }
            }
        } else {  // MODE 3: BN+ReLU into LDS, then adaptive-avg-pool(5)
#pragma unroll
            for (int st = 0; st < ST; ++st) {
                const int wl = wave * ST * 16 + st * 16 + n;
#pragma unroll
                for (int ct = 0; ct < CT; ++ct)
#pragma unroll
                    for (int e = 0; e < 4; ++e)
                        hb[wl][ct * 16 + kq * 4 + e] =
                            fmaxf(fmaf(scv[ct][e], acc[st][ct][e] + bi[ct][e], shv[ct][e]), 0.f);
            }
            __syncthreads();
            const int bs[5] = {0, 25, 51, 76, 102};
            const int be[5] = {26, 52, 77, 103, 128};
            for (int o = tid; o < 320; o += 256) {
                const int cc = o & 63, bin = o >> 6;
                float accp = 0.f;
                for (int w = bs[bin]; w < be[bin]; ++w) accp += hb[w][cc];
                kk[((long long)b * 64 + cc) * 5 + bin] = accp / (float)(be[bin] - bs[bin]);
            }
        }
    }
}

// center+normalize rows of h^T per (b,c), emit 5 window-sum terms. block per b.
__global__ void srow_t(const unsigned short* __restrict__ h, float* __restrict__ Sv)
{
    __shared__ float hbuf[128][64];
    __shared__ float red[4][64];
    __shared__ float mrow[64];
    const int b = blockIdx.x, tid = threadIdx.x;
    const int c = tid & 63, grp = tid >> 6;
    const uint2* yd = (const uint2*)(h + (long long)b * 128 * 64);
    for (int i = tid; i < 128 * 16; i += 256) {
        const int w = i >> 4, c4 = (i & 15) * 4;
        const uint2 v = yd[i];
        hbuf[w][c4 + 0] = bflo(v.x);
        hbuf[w][c4 + 1] = bfhi(v.x);
        hbuf[w][c4 + 2] = bflo(v.y);
        hbuf[w][c4 + 3] = bfhi(v.y);
    }
    __syncthreads();
    float s = 0.f;
    for (int w = grp * 32; w < grp * 32 + 32; ++w) s += hbuf[w][c];
    red[grp][c] = s;
    __syncthreads();
    if (tid < 64) mrow[tid] = (red[0][tid] + red[1][tid] + red[2][tid] + red[3][tid]) / 128.f;
    __syncthreads();
    const float m = mrow[c];
    float q = 0.f;
    for (int w = grp * 32; w < grp * 32 + 32; ++w) { const float d = hbuf[w][c] - m; q += d * d; }
    red[grp][c] = q;
    __syncthreads();
    if (tid < 64) {
        const float n2 = red[0][tid] + red[1][tid] + red[2][tid] + red[3][tid];
        const float n = fmaxf(sqrtf(n2), 1e-12f);
        const float m0 = mrow[tid];
        const float h0 = (hbuf[0][tid] - m0) / n, h1 = (hbuf[1][tid] - m0) / n;
        const float hN1 = (hbuf[127][tid] - m0) / n, hN2 = (hbuf[126][tid] - m0) / n;
        float* o = Sv + ((long long)b * 64 + tid) * 5;
        o[0] = -(hN2 + hN1); o[1] = -hN1; o[2] = 0.f; o[3] = -h0; o[4] = -(h0 + h1);
    }
}

// merged: blocks [0,128) = flatnorm (wave-per-row), [128,256) = knorm
__global__ void norm_both(const float* __restrict__ kk, float* __restrict__ kn,
                          float* __restrict__ ab)
{
    if (blockIdx.x < 128) {
        const int wave = threadIdx.x >> 6, lane = threadIdx.x & 63;
        const int row = blockIdx.x * 4 + wave;
        const float* p = kk + (long long)row * 320;
        float n2 = 0.f;
        for (int d = lane; d < 320; d += 64) n2 += p[d] * p[d];
#pragma unroll
        for (int m = 1; m < 64; m <<= 1) n2 += __shfl_xor(n2, m, 64);
        const float n = fmaxf(sqrtf(n2), 1e-12f);
        float* o = ab + (long long)row * 320;
        for (int d = lane; d < 320; d += 64) o[d] = p[d] / n;
    } else {
        const int i = (blockIdx.x - 128) * NTHR + threadIdx.x;
        const float* p = kk + (long long)i * 5;
        float m = 0.f;
        for (int t = 0; t < 5; ++t) m += p[t];
        m *= 0.2f;
        float v[5]; float n2 = 0.f;
        for (int t = 0; t < 5; ++t) { v[t] = p[t] - m; n2 += v[t] * v[t]; }
        float n = fmaxf(sqrtf(n2), 1e-12f);
        for (int t = 0; t < 5; ++t) kn[(long long)i * 5 + t] = v[t] / n;
    }
}

// fused similarity + per-row log-softmax diag. grid (256, 3), block 256.
__global__ void simdot_nce(const float* __restrict__ kn, const float* __restrict__ Sv,
                           const float* __restrict__ ab, float* __restrict__ lp)
{
    const int j = threadIdx.x;
    const int i = blockIdx.x;
    const int z = blockIdx.y;
    const float* a;
    const float* b;
    float coef;
    if (z == 0)      { a = kn + (long long)i * 320;         b = Sv + (long long)(256 + j) * 320; coef = 10.f / 128.f; }
    else if (z == 1) { a = kn + (long long)(256 + i) * 320; b = Sv + (long long)j * 320;         coef = 10.f / 128.f; }
    else             { a = ab + (long long)i * 320;         b = ab + (long long)(256 + j) * 320; coef = 10.f; }
    float acc = 0.f;
    for (int d = 0; d < 320; ++d) acc += a[d] * b[d];
    const float v = acc * coef;

    __shared__ float red[NTHR];
    __shared__ float sdiag;
    if (j == i) sdiag = v;
    red[j] = v;
    __syncthreads();
    for (int off = NTHR / 2; off > 0; off >>= 1) {
        if (j < off) red[j] = fmaxf(red[j], red[j + off]);
        __syncthreads();
    }
    const float mx = red[0];
    __syncthreads();
    red[j] = expf(v - mx);
    __syncthreads();
    for (int off = NTHR / 2; off > 0; off >>= 1) {
        if (j < off) red[j] += red[j + off];
        __syncthreads();
    }
    if (j == 0) lp[z * 256 + i] = sdiag - (mx + logf(red[0]));
}

// reduce lp -> final loss scalar
__global__ void final3(const float* __restrict__ lp, float* __restrict__ out)
{
    __shared__ float red[NTHR];
    const int tid = threadIdx.x;
    float l[3];
    for (int z = 0; z < 3; ++z) {
        red[tid] = lp[z * 256 + tid];
        __syncthreads();
        for (int off = NTHR / 2; off > 0; off >>= 1) {
            if (tid < off) red[tid] += red[tid + off];
            __syncthreads();
        }
        l[z] = red[0];
        __syncthreads();
    }
    if (tid == 0)
        out[0] = 0.5f * (-l[0] / 256.f - l[1] / 256.f) + 0.5f * (-l[2] / 256.f);
}

// ---------------------------------------------------------------------------

extern "C" void kernel_launch(void* const* d_in, const int* in_sizes, int n_in,
                              void* d_out, int out_size, void* d_ws, size_t ws_size,
                              hipStream_t stream)
{
    const float* x1  = (const float*)d_in[0];
    const float* x2  = (const float*)d_in[1];
    const float* w1  = (const float*)d_in[2];
    const float* b1  = (const float*)d_in[3];
    const float* g1  = (const float*)d_in[4];
    const float* be1 = (const float*)d_in[5];
    const float* w2  = (const float*)d_in[6];
    const float* b2  = (const float*)d_in[7];
    const float* g2  = (const float*)d_in[8];
    const float* be2 = (const float*)d_in[9];
    const float* w3  = (const float*)d_in[10];
    const float* b3  = (const float*)d_in[11];
    const float* g3  = (const float*)d_in[12];
    const float* be3 = (const float*)d_in[13];
    const float* tw1 = (const float*)d_in[14];
    const float* tb1 = (const float*)d_in[15];
    const float* tg1 = (const float*)d_in[16];
    const float* tbe1= (const float*)d_in[17];
    const float* tw2 = (const float*)d_in[18];
    const float* tb2 = (const float*)d_in[19];
    const float* tg2 = (const float*)d_in[20];
    const float* tbe2= (const float*)d_in[21];
    float* out = (float*)d_out;

    char* ws = (char*)d_ws;
    size_t off = 0;
    auto alloc = [&](size_t bytes) -> void* {
        off = (off + 255) & ~(size_t)255;
        void* p = ws + off;
        off += bytes;
        return p;
    };
    typedef unsigned short u16;
    u16* xT2  = (u16*)alloc((size_t)BSZ2 * 2048 * 16 * 2);  // stage1 out  33.6MB
    u16* s2o  = (u16*)alloc((size_t)BSZ2 * 512 * 32 * 2);   // stage2 out  16.8MB
    u16* hT   = (u16*)alloc((size_t)BSZ2 * 128 * 64 * 2);   // h (both)     8.4MB
    u16* t1o  = (u16*)alloc((size_t)BSZ2 * 128 * 64 * 2);   // t1 out       8.4MB
    u16* wp1  = (u16*)alloc((size_t)512 * 2);
    u16* wp2  = (u16*)alloc((size_t)9 * 1 * 2 * 512 * 2);
    u16* wp3  = (u16*)alloc((size_t)17 * 1 * 4 * 512 * 2);
    u16* wpt1 = (u16*)alloc((size_t)5 * 2 * 4 * 512 * 2);
    u16* wpt2 = (u16*)alloc((size_t)3 * 2 * 4 * 512 * 2);
    float* kk   = (float*)alloc((size_t)BSZ2 * 320 * 4);
    float* kn   = (float*)alloc((size_t)BSZ2 * 320 * 4);
    float* ab   = (float*)alloc((size_t)BSZ2 * 320 * 4);
    float* Sv   = (float*)alloc((size_t)BSZ2 * 320 * 4);
    float* lp   = (float*)alloc((size_t)3 * 256 * 4);
    float* partials = (float*)alloc((size_t)16384 * 16 * 2 * 4);  // 2 MB
    float* scale = (float*)alloc(2 * 64 * 4);
    float* shift = (float*)alloc(2 * 64 * 4);

    // all weight prepacks, one launch (77312 elements)
    build_all_wpacks<<<303, NTHR, 0, stream>>>(w1, w2, w3, tw1, tw2, wp1, wp2, wp3, wpt1, wpt2);

    // ---- stage 1: MFMA conv (1->16, K17 pad 32, W=8192), stats -> apply ----
    {
        const int nblk = BSZ2 * (8192 / 512);      // WT=8, CHUNK=512 -> 8192 blocks
        conv1_mfma<8, 0><<<nblk, 256, 0, stream>>>(x1, x2, wp1, b1, nullptr, nullptr, nullptr, partials);
        dim3 fg(16, 2);
        finalize2<16><<<fg, NTHR, 0, stream>>>(partials, nblk / 2, 1.f / ((float)256 * 8192), g1, be1, scale, shift);
        conv1_mfma<8, 1><<<nblk, 256, 0, stream>>>(x1, x2, wp1, b1, scale, shift, xT2, nullptr);
    }
    // ---- stage 2: MFMA conv (16->32, W=2048), stats -> apply(pool) ----
    {
        const int nblk = BSZ2 * (2048 / 256);
        conv_mfma<16,32,17,8,2,9,1,2,4,0><<<nblk, 256, 0, stream>>>(xT2, wp2, b2, nullptr, nullptr, nullptr, nullptr, partials, 2048);
        dim3 fg(32, 2);
        finalize2<32><<<fg, NTHR, 0, stream>>>(partials, nblk / 2, 1.f / ((float)256 * 2048), g2, be2, scale, shift);
        conv_mfma<16,32,17,8,2,9,1,2,4,1><<<nblk, 256, 0, stream>>>(xT2, wp2, b2, scale, shift, s2o, nullptr, nullptr, 2048);
    }
    // ---- stage 3: MFMA conv (32->64, W=512), stats -> apply(pool) ----
    {
        const int nblk = BSZ2 * (512 / 256);
        conv_mfma<32,64,17,8,1,17,1,4,4,0><<<nblk, 256, 0, stream>>>(s2o, wp3, b3, nullptr, nullptr, nullptr, nullptr, partials, 512);
        dim3 fg(64, 2);
        finalize2<64><<<fg, NTHR, 0, stream>>>(partials, nblk / 2, 1.f / ((float)256 * 512), g3, be3, scale, shift);
        conv_mfma<32,64,17,8,1,17,1,4,4,1><<<nblk, 256, 0, stream>>>(s2o, wp3, b3, scale, shift, hT, nullptr, nullptr, 512);
    }
    // ---- template stage 1: (64->64, K=5, W=128), stats -> apply ----
    {
        conv_mfma<64,64,5,2,1,5,2,4,2,0><<<BSZ2, 256, 0, stream>>>(hT, wpt1, tb1, nullptr, nullptr, nullptr, nullptr, partials, 128);
        dim3 fg(64, 2);
        finalize2<64><<<fg, NTHR, 0, stream>>>(partials, 256, 1.f / ((float)256 * 128), tg1, tbe1, scale, shift);
        conv_mfma<64,64,5,2,1,5,2,4,2,2><<<BSZ2, 256, 0, stream>>>(hT, wpt1, tb1, scale, shift, t1o, nullptr, nullptr, 128);
    }
    // ---- template stage 2: (64->64, K=3, W=128), stats -> apply(adapool) ----
    {
        conv_mfma<64,64,3,1,1,3,2,4,2,0><<<BSZ2, 256, 0, stream>>>(t1o, wpt2, tb2, nullptr, nullptr, nullptr, nullptr, partials, 128);
        dim3 fg(64, 2);
        finalize2<64><<<fg, NTHR, 0, stream>>>(partials, 256, 1.f / ((float)256 * 128), tg2, tbe2, scale, shift);
        conv_mfma<64,64,3,1,1,3,2,4,2,3><<<BSZ2, 256, 0, stream>>>(t1o, wpt2, tb2, scale, shift, nullptr, kk, nullptr, 128);
    }

    // ---- tail ----
    srow_t<<<BSZ2, 256, 0, stream>>>(hT, Sv);
    norm_both<<<256, NTHR, 0, stream>>>(kk, kn, ab);
    dim3 sg(256, 3);
    simdot_nce<<<sg, NTHR, 0, stream>>>(kn, Sv, ab, lp);
    final3<<<1, NTHR, 0, stream>>>(lp, out);
}

// Round 9
// 266.427 us; speedup vs baseline: 1.1292x; 1.1292x over previous
//
#include <hip/hip_runtime.h>
#include <hip/hip_bf16.h>
#include <math.h>

// ---------------------------------------------------------------------------
// TCCL model forward. Round 8 (hybrid):
//  - stage 1: MFMA recompute (R7) — conv cheap, avoids 134MB y
//  - stages 2,3,t1,t2: conv+bias -> y bf16 materialized WITH fused BN stats
//    (R6 structure; y write+read is cheaper than a second conv pass), then
//    vectorized bn_pool/bn_apply/bn_adapool
//  - R7 recompute-apply for big stages reverted (cost ~2x MFMA on stages 2/3;
//    R7 post-mortem: materialize wins when conv-GFLOP*us > y-bytes/6.3TB/s)
// ---------------------------------------------------------------------------

#define BSZ2 512          // combined batch (x1 ++ x2)
#define NTHR 256

typedef __attribute__((ext_vector_type(8))) short bf16x8;
typedef __attribute__((ext_vector_type(4))) float f32x4;

static inline int ceil_divll(long long a, int b) { return (int)((a + b - 1) / b); }

__device__ __forceinline__ unsigned short f2bf(float f) {
    unsigned u = __float_as_uint(f);
    u = (u + 0x7FFFu + ((u >> 16) & 1u)) >> 16;
    return (unsigned short)u;
}
__device__ __forceinline__ float bf2f(unsigned short h) {
    return __uint_as_float(((unsigned)h) << 16);
}
__device__ __forceinline__ float bflo(unsigned u) { return __uint_as_float(u << 16); }
__device__ __forceinline__ float bfhi(unsigned u) { return __uint_as_float(u & 0xFFFF0000u); }

// ---------------- stage 1 MFMA conv (Cin=1, K=17 padded to 32) --------------
// MODE 0 = stats partials; MODE 1 = BN+ReLU+maxpool4 -> bf16 [b][wp][16]
template<int WT, int MODE>
__global__ __launch_bounds__(256)
void conv1_mfma(const float* __restrict__ x1, const float* __restrict__ x2,
                const unsigned short* __restrict__ wpack1, const float* __restrict__ bias,
                const float* __restrict__ scale, const float* __restrict__ shift,
                unsigned short* __restrict__ out, float* __restrict__ partials)
{
    constexpr int W = 8192;
    constexpr int CHUNK = 4 * WT * 16;
    __shared__ float xs[CHUNK + 32];
    __shared__ float sred[(MODE == 0) ? 4 : 1][4][4];
    __shared__ float ssred[(MODE == 0) ? 4 : 1][4][4];

    const int tid = threadIdx.x;
    const int ntile = W / CHUNK;
    const int b = blockIdx.x / ntile;
    const int w0 = (blockIdx.x % ntile) * CHUNK;
    const float* xrow = (b < 256) ? x1 + (long long)b * W : x2 + (long long)(b - 256) * W;

    for (int i = tid; i < CHUNK + 32; i += 256) {
        const int gw = w0 - 8 + i;
        xs[i] = (gw >= 0 && gw < W) ? xrow[gw] : 0.f;
    }
    __syncthreads();

    const int lane = tid & 63, wave = tid >> 6;
    const int n = lane & 15, kq = lane >> 4;
    const bf16x8 a = *(const bf16x8*)(wpack1 + lane * 8);

    f32x4 acc[WT];
#pragma unroll
    for (int wt = 0; wt < WT; ++wt) { acc[wt][0]=0.f; acc[wt][1]=0.f; acc[wt][2]=0.f; acc[wt][3]=0.f; }

    const int base0 = wave * WT * 16 + n + kq * 8;
#pragma unroll
    for (int wt = 0; wt < WT; ++wt) {
        bf16x8 bv;
#pragma unroll
        for (int j = 0; j < 8; ++j) {
            __hip_bfloat16 h = __float2bfloat16(xs[base0 + wt * 16 + j]);
            bv[j] = *reinterpret_cast<short*>(&h);
        }
        acc[wt] = __builtin_amdgcn_mfma_f32_16x16x32_bf16(a, bv, acc[wt], 0, 0, 0);
    }

    if (MODE == 0) {
        float bi[4];
#pragma unroll
        for (int e = 0; e < 4; ++e) bi[e] = bias[kq * 4 + e];
        float s_[4], ss_[4];
#pragma unroll
        for (int e = 0; e < 4; ++e) { s_[e] = 0.f; ss_[e] = 0.f; }
#pragma unroll
        for (int wt = 0; wt < WT; ++wt)
#pragma unroll
            for (int e = 0; e < 4; ++e) {
                const float y = acc[wt][e] + bi[e];
                s_[e] += y; ss_[e] += y * y;
            }
#pragma unroll
        for (int m = 1; m < 16; m <<= 1) {
#pragma unroll
            for (int e = 0; e < 4; ++e) {
                s_[e]  += __shfl_xor(s_[e], m, 64);
                ss_[e] += __shfl_xor(ss_[e], m, 64);
            }
        }
        if (n == 0) {
#pragma unroll
            for (int e = 0; e < 4; ++e) { sred[wave][kq][e] = s_[e]; ssred[wave][kq][e] = ss_[e]; }
        }
        __syncthreads();
        if (tid < 16) {
            const int q = tid >> 2, e = tid & 3;
            float sumv = 0.f, sumsq = 0.f;
#pragma unroll
            for (int wv = 0; wv < 4; ++wv) { sumv += sred[wv][q][e]; sumsq += ssred[wv][q][e]; }
            partials[((long long)blockIdx.x * 16 + tid) * 2 + 0] = sumv;
            partials[((long long)blockIdx.x * 16 + tid) * 2 + 1] = sumsq;
        }
    } else {
        const int half = b >> 8;
        float bi[4], scv[4], shv[4];
#pragma unroll
        for (int e = 0; e < 4; ++e) {
            bi[e]  = bias[kq * 4 + e];
            scv[e] = scale[half * 16 + kq * 4 + e];
            shv[e] = shift[half * 16 + kq * 4 + e];
        }
#pragma unroll
        for (int wt = 0; wt < WT; ++wt) {
            float v[4];
#pragma unroll
            for (int e = 0; e < 4; ++e) {
                v[e] = fmaf(scv[e], acc[wt][e] + bi[e], shv[e]);
                v[e] = fmaxf(v[e], __shfl_xor(v[e], 1, 64));
                v[e] = fmaxf(v[e], __shfl_xor(v[e], 2, 64));
                v[e] = fmaxf(v[e], 0.f);
            }
            if ((n & 3) == 0) {
                const int wp = (w0 + wave * WT * 16 + wt * 16 + n) >> 2;
                uint2 pk;
                pk.x = (unsigned)f2bf(v[0]) | ((unsigned)f2bf(v[1]) << 16);
                pk.y = (unsigned)f2bf(v[2]) | ((unsigned)f2bf(v[3]) << 16);
                *(uint2*)(out + ((long long)b * 2048 + wp) * 16 + kq * 4) = pk;
            }
        }
    }
}

// per-channel, per-half finalize. grid (COUT, 2).
template<int COUT>
__global__ void finalize2(const float* __restrict__ partials, int nblk_half, float invN,
                          const float* __restrict__ g, const float* __restrict__ be,
                          float* __restrict__ scale, float* __restrict__ shift)
{
    const int co = blockIdx.x;
    const int half = blockIdx.y;
    const float* P = partials + (size_t)half * nblk_half * COUT * 2;
    float s = 0.f, ss = 0.f;
    for (int i = threadIdx.x; i < nblk_half; i += NTHR) {
        s  += P[((long long)i * COUT + co) * 2 + 0];
        ss += P[((long long)i * COUT + co) * 2 + 1];
    }
    __shared__ float red[NTHR][2];
    red[threadIdx.x][0] = s; red[threadIdx.x][1] = ss;
    __syncthreads();
    for (int off = NTHR / 2; off > 0; off >>= 1) {
        if ((int)threadIdx.x < off) {
            red[threadIdx.x][0] += red[threadIdx.x + off][0];
            red[threadIdx.x][1] += red[threadIdx.x + off][1];
        }
        __syncthreads();
    }
    if (threadIdx.x == 0) {
        const float m = red[0][0] * invN;
        const float v = red[0][1] * invN - m * m;
        const float inv = rsqrtf(v + 1e-5f);
        const float sc = g[co] * inv;
        scale[half * COUT + co] = sc;
        shift[half * COUT + co] = be[co] - sc * m;
    }
}

// ---------------- weight prepacks (one launch) ------------------------------
template<int CIN, int KK, int DT, int NP, int S, int CT>
__device__ __forceinline__ void pack_one(int idx, const float* __restrict__ wgt,
                                         unsigned short* __restrict__ wp)
{
    const int j = idx & 7;
    const int l = (idx >> 3) & 63;
    int rest = idx >> 9;
    const int ct = rest % CT; rest /= CT;
    const int s = rest % S;
    const int p = rest / S;
    const int co = ct * 16 + (l & 15);
    const int k = (l >> 4) * 8 + j;
    int ci, t;
    if (DT == 2) { ci = k & (CIN - 1); t = p * 2 + (k >> 4); }
    else         { ci = s * 32 + k;    t = p; }
    float v = (t < KK) ? wgt[((long long)co * CIN + ci) * KK + t] : 0.f;
    wp[idx] = f2bf(v);
}

__global__ void build_all_wpacks(const float* __restrict__ w1, const float* __restrict__ w2,
                                 const float* __restrict__ w3,
                                 const float* __restrict__ tw1, const float* __restrict__ tw2,
                                 unsigned short* __restrict__ wp1,
                                 unsigned short* __restrict__ wp2, unsigned short* __restrict__ wp3,
                                 unsigned short* __restrict__ wpt1, unsigned short* __restrict__ wpt2)
{
    const int idx = blockIdx.x * NTHR + threadIdx.x;
    const int n1 = 512;
    const int n2 = 9 * 1 * 2 * 512;
    const int n3 = 17 * 1 * 4 * 512;
    const int nt1 = 5 * 2 * 4 * 512;
    const int nt2 = 3 * 2 * 4 * 512;
    if (idx < n1) {
        const int j = idx & 7, l = idx >> 3;
        const int co = l & 15, k = (l >> 4) * 8 + j;
        wp1[idx] = f2bf((k < 17) ? w1[co * 17 + k] : 0.f);
    }
    else if (idx < n1 + n2) pack_one<16, 17, 2, 9, 1, 2>(idx - n1, w2, wp2);
    else if (idx < n1 + n2 + n3) pack_one<32, 17, 1, 17, 1, 4>(idx - n1 - n2, w3, wp3);
    else if (idx < n1 + n2 + n3 + nt1) pack_one<64, 5, 1, 5, 2, 4>(idx - n1 - n2 - n3, tw1, wpt1);
    else if (idx < n1 + n2 + n3 + nt1 + nt2) pack_one<64, 3, 1, 3, 2, 4>(idx - n1 - n2 - n3 - nt1, tw2, wpt2);
}

// ---------------- MFMA conv: y = conv+bias stored bf16 + fused BN stats -----
template<int CIN, int COUT, int KK, int PAD, int DT, int NP, int S, int CT, int ST>
__global__ __launch_bounds__(256)
void conv_mfma_y(const unsigned short* __restrict__ xT, const unsigned short* __restrict__ wpack,
                 const float* __restrict__ bias, unsigned short* __restrict__ yT,
                 float* __restrict__ partials, int W)
{
    constexpr int CHUNK = 4 * ST * 16;
    constexpr int ROWB = CIN * 2 + 16;
    constexpr int ROWS = CHUNK + KK + (DT - 1) + 1;
    constexpr int DPR = CIN / 2;
    __shared__ __align__(16) unsigned char lx[ROWS * ROWB];
    __shared__ float sred[4][CT][4][4];
    __shared__ float ssred[4][CT][4][4];

    const int tid = threadIdx.x;
    const int ntile = W / CHUNK;
    const int b = blockIdx.x / ntile;
    const int tile = blockIdx.x % ntile;
    const int w0 = tile * CHUNK;

    for (int d = tid; d < ROWS * DPR; d += 256) {
        const int row = d / DPR;
        const int col = d % DPR;
        const int gw = w0 - PAD + row;
        unsigned v = 0;
        if (gw >= 0 && gw < W)
            v = *(const unsigned*)(xT + (((long long)b * W + gw) * CIN + col * 2));
        *(unsigned*)(lx + row * ROWB + col * 4) = v;
    }
    __syncthreads();

    const int lane = tid & 63, wave = tid >> 6;
    const int n = lane & 15, kq = lane >> 4;
    int rowbase, cbyte;
    if (DT == 2) { rowbase = wave * ST * 16 + n + (kq >> 1); cbyte = (kq & 1) * 16; }
    else         { rowbase = wave * ST * 16 + n;             cbyte = kq * 16; }

    f32x4 acc[ST][CT];
#pragma unroll
    for (int st = 0; st < ST; ++st)
#pragma unroll
        for (int ct = 0; ct < CT; ++ct) { acc[st][ct][0]=0.f; acc[st][ct][1]=0.f; acc[st][ct][2]=0.f; acc[st][ct][3]=0.f; }

#pragma unroll
    for (int p = 0; p < NP; ++p) {
#pragma unroll
        for (int s = 0; s < S; ++s) {
            bf16x8 a[CT];
#pragma unroll
            for (int ct = 0; ct < CT; ++ct)
                a[ct] = *(const bf16x8*)(wpack + (((long long)(p * S + s) * CT + ct) * 64 + lane) * 8);
#pragma unroll
            for (int st = 0; st < ST; ++st) {
                const int r = rowbase + st * 16 + p * DT;
                const bf16x8 bf = *(const bf16x8*)(lx + r * ROWB + cbyte + s * 64);
#pragma unroll
                for (int ct = 0; ct < CT; ++ct)
                    acc[st][ct] = __builtin_amdgcn_mfma_f32_16x16x32_bf16(a[ct], bf, acc[st][ct], 0, 0, 0);
            }
        }
    }

    float s_[CT][4], ss_[CT][4];
#pragma unroll
    for (int ct = 0; ct < CT; ++ct)
#pragma unroll
        for (int e = 0; e < 4; ++e) { s_[ct][e] = 0.f; ss_[ct][e] = 0.f; }

#pragma unroll
    for (int st = 0; st < ST; ++st) {
        const int w = w0 + wave * ST * 16 + st * 16 + n;
        unsigned short* orow = yT + ((long long)b * W + w) * COUT;
#pragma unroll
        for (int ct = 0; ct < CT; ++ct) {
            const float* bp = bias + ct * 16 + kq * 4;
            float v[4];
#pragma unroll
            for (int e = 0; e < 4; ++e) {
                v[e] = acc[st][ct][e] + bp[e];
                s_[ct][e] += v[e];
                ss_[ct][e] += v[e] * v[e];
            }
            uint2 pk;
            pk.x = (unsigned)f2bf(v[0]) | ((unsigned)f2bf(v[1]) << 16);
            pk.y = (unsigned)f2bf(v[2]) | ((unsigned)f2bf(v[3]) << 16);
            *(uint2*)(orow + ct * 16 + kq * 4) = pk;
        }
    }
#pragma unroll
    for (int m = 1; m < 16; m <<= 1) {
#pragma unroll
        for (int ct = 0; ct < CT; ++ct)
#pragma unroll
            for (int e = 0; e < 4; ++e) {
                s_[ct][e]  += __shfl_xor(s_[ct][e], m, 64);
                ss_[ct][e] += __shfl_xor(ss_[ct][e], m, 64);
            }
    }
    if (n == 0) {
#pragma unroll
        for (int ct = 0; ct < CT; ++ct)
#pragma unroll
            for (int e = 0; e < 4; ++e) {
                sred[wave][ct][kq][e] = s_[ct][e];
                ssred[wave][ct][kq][e] = ss_[ct][e];
            }
    }
    __syncthreads();
    if (tid < COUT) {
        const int ct = tid >> 4, q = (tid >> 2) & 3, e = tid & 3;
        float sumv = 0.f, sumsq = 0.f;
#pragma unroll
        for (int wv = 0; wv < 4; ++wv) { sumv += sred[wv][ct][q][e]; sumsq += ssred[wv][ct][q][e]; }
        partials[((long long)blockIdx.x * COUT + tid) * 2 + 0] = sumv;
        partials[((long long)blockIdx.x * COUT + tid) * 2 + 1] = sumsq;
    }
}

// BN+ReLU+maxpool4 on transposed y, channel-pair vectorized.
template<int C, int W>
__global__ void bn_pool_t(const unsigned short* __restrict__ y, const float* __restrict__ scale,
                          const float* __restrict__ shift, unsigned short* __restrict__ out)
{
    constexpr int WP = W / 4;
    constexpr int C2 = C / 2;
    const int total = BSZ2 * WP * C2;
    const unsigned* yd = (const unsigned*)y;
    unsigned* od = (unsigned*)out;
    for (int idx = blockIdx.x * NTHR + threadIdx.x; idx < total; idx += gridDim.x * NTHR) {
        const int c2 = idx % C2;
        const int rest = idx / C2;
        const int wp = rest % WP;
        const int b = rest / WP;
        const int c0 = 2 * c2;
        const float sc0 = scale[(b >> 8) * C + c0], sh0 = shift[(b >> 8) * C + c0];
        const float sc1 = scale[(b >> 8) * C + c0 + 1], sh1 = shift[(b >> 8) * C + c0 + 1];
        const long long base = (((long long)b * W + 4 * wp) * C) / 2 + c2;
        float m0 = 0.f, m1 = 0.f;
#pragma unroll
        for (int q = 0; q < 4; ++q) {
            const unsigned v = yd[base + (long long)q * C2];
            m0 = fmaxf(m0, fmaf(sc0, bflo(v), sh0));
            m1 = fmaxf(m1, fmaf(sc1, bfhi(v), sh1));
        }
        od[idx] = (unsigned)f2bf(m0) | ((unsigned)f2bf(m1) << 16);
    }
}

// BN+ReLU (no pool), 4-channel vectorized.
template<int C, int W>
__global__ void bn_apply_t(const unsigned short* __restrict__ y, const float* __restrict__ scale,
                           const float* __restrict__ shift, unsigned short* __restrict__ out)
{
    constexpr int C4 = C / 4;
    const int total = BSZ2 * W * C4;
    const uint2* yd = (const uint2*)y;
    uint2* od = (uint2*)out;
    for (int idx = blockIdx.x * NTHR + threadIdx.x; idx < total; idx += gridDim.x * NTHR) {
        const int c4 = idx % C4;
        const int b = idx / (W * C4);
        const int c0 = 4 * c4;
        const float* scp = scale + (b >> 8) * C + c0;
        const float* shp = shift + (b >> 8) * C + c0;
        const uint2 v = yd[idx];
        const float r0 = fmaxf(fmaf(scp[0], bflo(v.x), shp[0]), 0.f);
        const float r1 = fmaxf(fmaf(scp[1], bfhi(v.x), shp[1]), 0.f);
        const float r2 = fmaxf(fmaf(scp[2], bflo(v.y), shp[2]), 0.f);
        const float r3 = fmaxf(fmaf(scp[3], bfhi(v.y), shp[3]), 0.f);
        uint2 o;
        o.x = (unsigned)f2bf(r0) | ((unsigned)f2bf(r1) << 16);
        o.y = (unsigned)f2bf(r2) | ((unsigned)f2bf(r3) << 16);
        od[idx] = o;
    }
}

// BN+ReLU + adaptive-avg-pool(5); block per batch row. y: [b][128][64] bf16
__global__ void bn_adapool_t(const unsigned short* __restrict__ y, const float* __restrict__ scale,
                             const float* __restrict__ shift, float* __restrict__ kk)
{
    __shared__ float hb[128][64];
    const int b = blockIdx.x, tid = threadIdx.x;
    const uint2* yd = (const uint2*)(y + (long long)b * 128 * 64);
    for (int i = tid; i < 128 * 16; i += 256) {
        const int w = i >> 4, c4 = (i & 15) * 4;
        const float* scp = scale + (b >> 8) * 64 + c4;
        const float* shp = shift + (b >> 8) * 64 + c4;
        const uint2 v = yd[i];
        hb[w][c4 + 0] = fmaxf(fmaf(scp[0], bflo(v.x), shp[0]), 0.f);
        hb[w][c4 + 1] = fmaxf(fmaf(scp[1], bfhi(v.x), shp[1]), 0.f);
        hb[w][c4 + 2] = fmaxf(fmaf(scp[2], bflo(v.y), shp[2]), 0.f);
        hb[w][c4 + 3] = fmaxf(fmaf(scp[3], bfhi(v.y), shp[3]), 0.f);
    }
    __syncthreads();
    const int bs[5] = {0, 25, 51, 76, 102};
    const int be[5] = {26, 52, 77, 103, 128};
    for (int o = tid; o < 320; o += 256) {
        const int cc = o & 63, bin = o >> 6;
        float acc = 0.f;
        for (int w = bs[bin]; w < be[bin]; ++w) acc += hb[w][cc];
        kk[((long long)b * 64 + cc) * 5 + bin] = acc / (float)(be[bin] - bs[bin]);
    }
}

// center+normalize rows of h^T per (b,c), emit 5 window-sum terms. block per b.
__global__ void srow_t(const unsigned short* __restrict__ h, float* __restrict__ Sv)
{
    __shared__ float hbuf[128][64];
    __shared__ float red[4][64];
    __shared__ float mrow[64];
    const int b = blockIdx.x, tid = threadIdx.x;
    const int c = tid & 63, grp = tid >> 6;
    const uint2* yd = (const uint2*)(h + (long long)b * 128 * 64);
    for (int i = tid; i < 128 * 16; i += 256) {
        const int w = i >> 4, c4 = (i & 15) * 4;
        const uint2 v = yd[i];
        hbuf[w][c4 + 0] = bflo(v.x);
        hbuf[w][c4 + 1] = bfhi(v.x);
        hbuf[w][c4 + 2] = bflo(v.y);
        hbuf[w][c4 + 3] = bfhi(v.y);
    }
    __syncthreads();
    float s = 0.f;
    for (int w = grp * 32; w < grp * 32 + 32; ++w) s += hbuf[w][c];
    red[grp][c] = s;
    __syncthreads();
    if (tid < 64) mrow[tid] = (red[0][tid] + red[1][tid] + red[2][tid] + red[3][tid]) / 128.f;
    __syncthreads();
    const float m = mrow[c];
    float q = 0.f;
    for (int w = grp * 32; w < grp * 32 + 32; ++w) { const float d = hbuf[w][c] - m; q += d * d; }
    red[grp][c] = q;
    __syncthreads();
    if (tid < 64) {
        const float n2 = red[0][tid] + red[1][tid] + red[2][tid] + red[3][tid];
        const float n = fmaxf(sqrtf(n2), 1e-12f);
        const float m0 = mrow[tid];
        const float h0 = (hbuf[0][tid] - m0) / n, h1 = (hbuf[1][tid] - m0) / n;
        const float hN1 = (hbuf[127][tid] - m0) / n, hN2 = (hbuf[126][tid] - m0) / n;
        float* o = Sv + ((long long)b * 64 + tid) * 5;
        o[0] = -(hN2 + hN1); o[1] = -hN1; o[2] = 0.f; o[3] = -h0; o[4] = -(h0 + h1);
    }
}

// merged: blocks [0,128) = flatnorm (wave-per-row), [128,256) = knorm
__global__ void norm_both(const float* __restrict__ kk, float* __restrict__ kn,
                          float* __restrict__ ab)
{
    if (blockIdx.x < 128) {
        const int wave = threadIdx.x >> 6, lane = threadIdx.x & 63;
        const int row = blockIdx.x * 4 + wave;
        const float* p = kk + (long long)row * 320;
        float n2 = 0.f;
        for (int d = lane; d < 320; d += 64) n2 += p[d] * p[d];
#pragma unroll
        for (int m = 1; m < 64; m <<= 1) n2 += __shfl_xor(n2, m, 64);
        const float n = fmaxf(sqrtf(n2), 1e-12f);
        float* o = ab + (long long)row * 320;
        for (int d = lane; d < 320; d += 64) o[d] = p[d] / n;
    } else {
        const int i = (blockIdx.x - 128) * NTHR + threadIdx.x;
        const float* p = kk + (long long)i * 5;
        float m = 0.f;
        for (int t = 0; t < 5; ++t) m += p[t];
        m *= 0.2f;
        float v[5]; float n2 = 0.f;
        for (int t = 0; t < 5; ++t) { v[t] = p[t] - m; n2 += v[t] * v[t]; }
        float n = fmaxf(sqrtf(n2), 1e-12f);
        for (int t = 0; t < 5; ++t) kn[(long long)i * 5 + t] = v[t] / n;
    }
}

// fused similarity + per-row log-softmax diag. grid (256, 3), block 256.
__global__ void simdot_nce(const float* __restrict__ kn, const float* __restrict__ Sv,
                           const float* __restrict__ ab, float* __restrict__ lp)
{
    const int j = threadIdx.x;
    const int i = blockIdx.x;
    const int z = blockIdx.y;
    const float* a;
    const float* b;
    float coef;
    if (z == 0)      { a = kn + (long long)i * 320;         b = Sv + (long long)(256 + j) * 320; coef = 10.f / 128.f; }
    else if (z == 1) { a = kn + (long long)(256 + i) * 320; b = Sv + (long long)j * 320;         coef = 10.f / 128.f; }
    else             { a = ab + (long long)i * 320;         b = ab + (long long)(256 + j) * 320; coef = 10.f; }
    float acc = 0.f;
    for (int d = 0; d < 320; ++d) acc += a[d] * b[d];
    const float v = acc * coef;

    __shared__ float red[NTHR];
    __shared__ float sdiag;
    if (j == i) sdiag = v;
    red[j] = v;
    __syncthreads();
    for (int off = NTHR / 2; off > 0; off >>= 1) {
        if (j < off) red[j] = fmaxf(red[j], red[j + off]);
        __syncthreads();
    }
    const float mx = red[0];
    __syncthreads();
    red[j] = expf(v - mx);
    __syncthreads();
    for (int off = NTHR / 2; off > 0; off >>= 1) {
        if (j < off) red[j] += red[j + off];
        __syncthreads();
    }
    if (j == 0) lp[z * 256 + i] = sdiag - (mx + logf(red[0]));
}

// reduce lp -> final loss scalar
__global__ void final3(const float* __restrict__ lp, float* __restrict__ out)
{
    __shared__ float red[NTHR];
    const int tid = threadIdx.x;
    float l[3];
    for (int z = 0; z < 3; ++z) {
        red[tid] = lp[z * 256 + tid];
        __syncthreads();
        for (int off = NTHR / 2; off > 0; off >>= 1) {
            if (tid < off) red[tid] += red[tid + off];
            __syncthreads();
        }
        l[z] = red[0];
        __syncthreads();
    }
    if (tid == 0)
        out[0] = 0.5f * (-l[0] / 256.f - l[1] / 256.f) + 0.5f * (-l[2] / 256.f);
}

// ---------------------------------------------------------------------------

extern "C" void kernel_launch(void* const* d_in, const int* in_sizes, int n_in,
                              void* d_out, int out_size, void* d_ws, size_t ws_size,
                              hipStream_t stream)
{
    const float* x1  = (const float*)d_in[0];
    const float* x2  = (const float*)d_in[1];
    const float* w1  = (const float*)d_in[2];
    const float* b1  = (const float*)d_in[3];
    const float* g1  = (const float*)d_in[4];
    const float* be1 = (const float*)d_in[5];
    const float* w2  = (const float*)d_in[6];
    const float* b2  = (const float*)d_in[7];
    const float* g2  = (const float*)d_in[8];
    const float* be2 = (const float*)d_in[9];
    const float* w3  = (const float*)d_in[10];
    const float* b3  = (const float*)d_in[11];
    const float* g3  = (const float*)d_in[12];
    const float* be3 = (const float*)d_in[13];
    const float* tw1 = (const float*)d_in[14];
    const float* tb1 = (const float*)d_in[15];
    const float* tg1 = (const float*)d_in[16];
    const float* tbe1= (const float*)d_in[17];
    const float* tw2 = (const float*)d_in[18];
    const float* tb2 = (const float*)d_in[19];
    const float* tg2 = (const float*)d_in[20];
    const float* tbe2= (const float*)d_in[21];
    float* out = (float*)d_out;

    char* ws = (char*)d_ws;
    size_t off = 0;
    auto alloc = [&](size_t bytes) -> void* {
        off = (off + 255) & ~(size_t)255;
        void* p = ws + off;
        off += bytes;
        return p;
    };
    typedef unsigned short u16;
    u16* xT2  = (u16*)alloc((size_t)BSZ2 * 2048 * 16 * 2);  // stage1 out  33.6MB
    u16* bigY = (u16*)alloc((size_t)BSZ2 * 2048 * 32 * 2);  // y scratch   67MB (reused)
    u16* s2o  = (u16*)alloc((size_t)BSZ2 * 512 * 32 * 2);   // stage2 out  16.8MB
    u16* hT   = (u16*)alloc((size_t)BSZ2 * 128 * 64 * 2);   // h (both)     8.4MB
    u16* t1o  = (u16*)alloc((size_t)BSZ2 * 128 * 64 * 2);   // t1 out       8.4MB
    u16* wp1  = (u16*)alloc((size_t)512 * 2);
    u16* wp2  = (u16*)alloc((size_t)9 * 1 * 2 * 512 * 2);
    u16* wp3  = (u16*)alloc((size_t)17 * 1 * 4 * 512 * 2);
    u16* wpt1 = (u16*)alloc((size_t)5 * 2 * 4 * 512 * 2);
    u16* wpt2 = (u16*)alloc((size_t)3 * 2 * 4 * 512 * 2);
    float* kk   = (float*)alloc((size_t)BSZ2 * 320 * 4);
    float* kn   = (float*)alloc((size_t)BSZ2 * 320 * 4);
    float* ab   = (float*)alloc((size_t)BSZ2 * 320 * 4);
    float* Sv   = (float*)alloc((size_t)BSZ2 * 320 * 4);
    float* lp   = (float*)alloc((size_t)3 * 256 * 4);
    float* partials = (float*)alloc((size_t)16384 * 16 * 2 * 4);  // 2 MB
    float* scale = (float*)alloc(2 * 64 * 4);
    float* shift = (float*)alloc(2 * 64 * 4);

    // all weight prepacks, one launch
    build_all_wpacks<<<303, NTHR, 0, stream>>>(w1, w2, w3, tw1, tw2, wp1, wp2, wp3, wpt1, wpt2);

    // ---- stage 1: MFMA conv (1->16), stats -> finalize -> apply(pool) ----
    {
        const int nblk = BSZ2 * (8192 / 512);
        conv1_mfma<8, 0><<<nblk, 256, 0, stream>>>(x1, x2, wp1, b1, nullptr, nullptr, nullptr, partials);
        dim3 fg(16, 2);
        finalize2<16><<<fg, NTHR, 0, stream>>>(partials, nblk / 2, 1.f / ((float)256 * 8192), g1, be1, scale, shift);
        conv1_mfma<8, 1><<<nblk, 256, 0, stream>>>(x1, x2, wp1, b1, scale, shift, xT2, nullptr);
    }
    // ---- stage 2: conv->y + stats, finalize, bn_pool ----
    {
        const int nblk = BSZ2 * (2048 / 256);
        conv_mfma_y<16,32,17,8,2,9,1,2,4><<<nblk, 256, 0, stream>>>(xT2, wp2, b2, bigY, partials, 2048);
        dim3 fg(32, 2);
        finalize2<32><<<fg, NTHR, 0, stream>>>(partials, nblk / 2, 1.f / ((float)256 * 2048), g2, be2, scale, shift);
        bn_pool_t<32, 2048><<<2048, NTHR, 0, stream>>>(bigY, scale, shift, s2o);
    }
    // ---- stage 3: conv->y + stats, finalize, bn_pool ----
    {
        const int nblk = BSZ2 * (512 / 256);
        conv_mfma_y<32,64,17,8,1,17,1,4,4><<<nblk, 256, 0, stream>>>(s2o, wp3, b3, bigY, partials, 512);
        dim3 fg(64, 2);
        finalize2<64><<<fg, NTHR, 0, stream>>>(partials, nblk / 2, 1.f / ((float)256 * 512), g3, be3, scale, shift);
        bn_pool_t<64, 512><<<2048, NTHR, 0, stream>>>(bigY, scale, shift, hT);
    }
    // ---- template stage 1: conv->y + stats, finalize, bn_apply ----
    {
        conv_mfma_y<64,64,5,2,1,5,2,4,2><<<BSZ2, 256, 0, stream>>>(hT, wpt1, tb1, bigY, partials, 128);
        dim3 fg(64, 2);
        finalize2<64><<<fg, NTHR, 0, stream>>>(partials, 256, 1.f / ((float)256 * 128), tg1, tbe1, scale, shift);
        bn_apply_t<64, 128><<<2048, NTHR, 0, stream>>>(bigY, scale, shift, t1o);
    }
    // ---- template stage 2: conv->y + stats, finalize, bn_adapool ----
    {
        conv_mfma_y<64,64,3,1,1,3,2,4,2><<<BSZ2, 256, 0, stream>>>(t1o, wpt2, tb2, bigY, partials, 128);
        dim3 fg(64, 2);
        finalize2<64><<<fg, NTHR, 0, stream>>>(partials, 256, 1.f / ((float)256 * 128), tg2, tbe2, scale, shift);
        bn_adapool_t<<<BSZ2, 256, 0, stream>>>(bigY, scale, shift, kk);
    }

    // ---- tail ----
    srow_t<<<BSZ2, 256, 0, stream>>>(hT, Sv);
    norm_both<<<256, NTHR, 0, stream>>>(kk, kn, ab);
    dim3 sg(256, 3);
    simdot_nce<<<sg, NTHR, 0, stream>>>(kn, Sv, ab, lp);
    final3<<<1, NTHR, 0, stream>>>(lp, out);
}

// Round 10
// 260.041 us; speedup vs baseline: 1.1570x; 1.0246x over previous
//
#include <hip/hip_runtime.h>
#include <hip/hip_bf16.h>
#include <math.h>

// ---------------------------------------------------------------------------
// TCCL model forward. Round 9:
//  - pooled min/max epilogue for stages 2,3 (maxpool∘relu∘affine commutes:
//    keep per-window max&min of raw y -> 4x less y traffic; R8 post-mortem
//    showed stage2 conv is HBM-bound on the 67MB y write)
//  - BN apply fused into the NEXT stage's LDS staging (select-by-sign +
//    relu while filling LDS); bn_pool/bn_apply kernels deleted
//  - per-stage scale/shift slots; srow+adapool fused into one kernel
//  - 16 launches (was 21)
// ---------------------------------------------------------------------------

#define BSZ2 512          // combined batch (x1 ++ x2)
#define NTHR 256

typedef __attribute__((ext_vector_type(8))) short bf16x8;
typedef __attribute__((ext_vector_type(4))) float f32x4;

static inline int ceil_divll(long long a, int b) { return (int)((a + b - 1) / b); }

__device__ __forceinline__ unsigned short f2bf(float f) {
    unsigned u = __float_as_uint(f);
    u = (u + 0x7FFFu + ((u >> 16) & 1u)) >> 16;
    return (unsigned short)u;
}
__device__ __forceinline__ float bf2f(unsigned short h) {
    return __uint_as_float(((unsigned)h) << 16);
}
__device__ __forceinline__ float bflo(unsigned u) { return __uint_as_float(u << 16); }
__device__ __forceinline__ float bfhi(unsigned u) { return __uint_as_float(u & 0xFFFF0000u); }

// ---------------- stage 1 MFMA conv (Cin=1, K=17 padded to 32) --------------
// MODE 0 = stats partials; MODE 1 = BN+ReLU+maxpool4 -> bf16 [b][wp][16]
template<int WT, int MODE>
__global__ __launch_bounds__(256)
void conv1_mfma(const float* __restrict__ x1, const float* __restrict__ x2,
                const unsigned short* __restrict__ wpack1, const float* __restrict__ bias,
                const float* __restrict__ scale, const float* __restrict__ shift,
                unsigned short* __restrict__ out, float* __restrict__ partials)
{
    constexpr int W = 8192;
    constexpr int CHUNK = 4 * WT * 16;
    __shared__ float xs[CHUNK + 32];
    __shared__ float sred[(MODE == 0) ? 4 : 1][4][4];
    __shared__ float ssred[(MODE == 0) ? 4 : 1][4][4];

    const int tid = threadIdx.x;
    const int ntile = W / CHUNK;
    const int b = blockIdx.x / ntile;
    const int w0 = (blockIdx.x % ntile) * CHUNK;
    const float* xrow = (b < 256) ? x1 + (long long)b * W : x2 + (long long)(b - 256) * W;

    for (int i = tid; i < CHUNK + 32; i += 256) {
        const int gw = w0 - 8 + i;
        xs[i] = (gw >= 0 && gw < W) ? xrow[gw] : 0.f;
    }
    __syncthreads();

    const int lane = tid & 63, wave = tid >> 6;
    const int n = lane & 15, kq = lane >> 4;
    const bf16x8 a = *(const bf16x8*)(wpack1 + lane * 8);

    f32x4 acc[WT];
#pragma unroll
    for (int wt = 0; wt < WT; ++wt) { acc[wt][0]=0.f; acc[wt][1]=0.f; acc[wt][2]=0.f; acc[wt][3]=0.f; }

    const int base0 = wave * WT * 16 + n + kq * 8;
#pragma unroll
    for (int wt = 0; wt < WT; ++wt) {
        bf16x8 bv;
#pragma unroll
        for (int j = 0; j < 8; ++j) {
            __hip_bfloat16 h = __float2bfloat16(xs[base0 + wt * 16 + j]);
            bv[j] = *reinterpret_cast<short*>(&h);
        }
        acc[wt] = __builtin_amdgcn_mfma_f32_16x16x32_bf16(a, bv, acc[wt], 0, 0, 0);
    }

    if (MODE == 0) {
        float bi[4];
#pragma unroll
        for (int e = 0; e < 4; ++e) bi[e] = bias[kq * 4 + e];
        float s_[4], ss_[4];
#pragma unroll
        for (int e = 0; e < 4; ++e) { s_[e] = 0.f; ss_[e] = 0.f; }
#pragma unroll
        for (int wt = 0; wt < WT; ++wt)
#pragma unroll
            for (int e = 0; e < 4; ++e) {
                const float y = acc[wt][e] + bi[e];
                s_[e] += y; ss_[e] += y * y;
            }
#pragma unroll
        for (int m = 1; m < 16; m <<= 1) {
#pragma unroll
            for (int e = 0; e < 4; ++e) {
                s_[e]  += __shfl_xor(s_[e], m, 64);
                ss_[e] += __shfl_xor(ss_[e], m, 64);
            }
        }
        if (n == 0) {
#pragma unroll
            for (int e = 0; e < 4; ++e) { sred[wave][kq][e] = s_[e]; ssred[wave][kq][e] = ss_[e]; }
        }
        __syncthreads();
        if (tid < 16) {
            const int q = tid >> 2, e = tid & 3;
            float sumv = 0.f, sumsq = 0.f;
#pragma unroll
            for (int wv = 0; wv < 4; ++wv) { sumv += sred[wv][q][e]; sumsq += ssred[wv][q][e]; }
            partials[((long long)blockIdx.x * 16 + tid) * 2 + 0] = sumv;
            partials[((long long)blockIdx.x * 16 + tid) * 2 + 1] = sumsq;
        }
    } else {
        const int half = b >> 8;
        float bi[4], scv[4], shv[4];
#pragma unroll
        for (int e = 0; e < 4; ++e) {
            bi[e]  = bias[kq * 4 + e];
            scv[e] = scale[half * 16 + kq * 4 + e];
            shv[e] = shift[half * 16 + kq * 4 + e];
        }
#pragma unroll
        for (int wt = 0; wt < WT; ++wt) {
            float v[4];
#pragma unroll
            for (int e = 0; e < 4; ++e) {
                v[e] = fmaf(scv[e], acc[wt][e] + bi[e], shv[e]);
                v[e] = fmaxf(v[e], __shfl_xor(v[e], 1, 64));
                v[e] = fmaxf(v[e], __shfl_xor(v[e], 2, 64));
                v[e] = fmaxf(v[e], 0.f);
            }
            if ((n & 3) == 0) {
                const int wp = (w0 + wave * WT * 16 + wt * 16 + n) >> 2;
                uint2 pk;
                pk.x = (unsigned)f2bf(v[0]) | ((unsigned)f2bf(v[1]) << 16);
                pk.y = (unsigned)f2bf(v[2]) | ((unsigned)f2bf(v[3]) << 16);
                *(uint2*)(out + ((long long)b * 2048 + wp) * 16 + kq * 4) = pk;
            }
        }
    }
}

// per-channel, per-half finalize. grid (COUT, 2).
template<int COUT>
__global__ void finalize2(const float* __restrict__ partials, int nblk_half, float invN,
                          const float* __restrict__ g, const float* __restrict__ be,
                          float* __restrict__ scale, float* __restrict__ shift)
{
    const int co = blockIdx.x;
    const int half = blockIdx.y;
    const float* P = partials + (size_t)half * nblk_half * COUT * 2;
    float s = 0.f, ss = 0.f;
    for (int i = threadIdx.x; i < nblk_half; i += NTHR) {
        s  += P[((long long)i * COUT + co) * 2 + 0];
        ss += P[((long long)i * COUT + co) * 2 + 1];
    }
    __shared__ float red[NTHR][2];
    red[threadIdx.x][0] = s; red[threadIdx.x][1] = ss;
    __syncthreads();
    for (int off = NTHR / 2; off > 0; off >>= 1) {
        if ((int)threadIdx.x < off) {
            red[threadIdx.x][0] += red[threadIdx.x + off][0];
            red[threadIdx.x][1] += red[threadIdx.x + off][1];
        }
        __syncthreads();
    }
    if (threadIdx.x == 0) {
        const float m = red[0][0] * invN;
        const float v = red[0][1] * invN - m * m;
        const float inv = rsqrtf(v + 1e-5f);
        const float sc = g[co] * inv;
        scale[half * COUT + co] = sc;
        shift[half * COUT + co] = be[co] - sc * m;
    }
}

// ---------------- weight prepacks (one launch) ------------------------------
template<int CIN, int KK, int DT, int NP, int S, int CT>
__device__ __forceinline__ void pack_one(int idx, const float* __restrict__ wgt,
                                         unsigned short* __restrict__ wp)
{
    const int j = idx & 7;
    const int l = (idx >> 3) & 63;
    int rest = idx >> 9;
    const int ct = rest % CT; rest /= CT;
    const int s = rest % S;
    const int p = rest / S;
    const int co = ct * 16 + (l & 15);
    const int k = (l >> 4) * 8 + j;
    int ci, t;
    if (DT == 2) { ci = k & (CIN - 1); t = p * 2 + (k >> 4); }
    else         { ci = s * 32 + k;    t = p; }
    float v = (t < KK) ? wgt[((long long)co * CIN + ci) * KK + t] : 0.f;
    wp[idx] = f2bf(v);
}

__global__ void build_all_wpacks(const float* __restrict__ w1, const float* __restrict__ w2,
                                 const float* __restrict__ w3,
                                 const float* __restrict__ tw1, const float* __restrict__ tw2,
                                 unsigned short* __restrict__ wp1,
                                 unsigned short* __restrict__ wp2, unsigned short* __restrict__ wp3,
                                 unsigned short* __restrict__ wpt1, unsigned short* __restrict__ wpt2)
{
    const int idx = blockIdx.x * NTHR + threadIdx.x;
    const int n1 = 512;
    const int n2 = 9 * 1 * 2 * 512;
    const int n3 = 17 * 1 * 4 * 512;
    const int nt1 = 5 * 2 * 4 * 512;
    const int nt2 = 3 * 2 * 4 * 512;
    if (idx < n1) {
        const int j = idx & 7, l = idx >> 3;
        const int co = l & 15, k = (l >> 4) * 8 + j;
        wp1[idx] = f2bf((k < 17) ? w1[co * 17 + k] : 0.f);
    }
    else if (idx < n1 + n2) pack_one<16, 17, 2, 9, 1, 2>(idx - n1, w2, wp2);
    else if (idx < n1 + n2 + n3) pack_one<32, 17, 1, 17, 1, 4>(idx - n1 - n2, w3, wp3);
    else if (idx < n1 + n2 + n3 + nt1) pack_one<64, 5, 1, 5, 2, 4>(idx - n1 - n2 - n3, tw1, wpt1);
    else if (idx < n1 + n2 + n3 + nt1 + nt2) pack_one<64, 3, 1, 3, 2, 4>(idx - n1 - n2 - n3 - nt1, tw2, wpt2);
}

// ---------------- MFMA conv, generalized ------------------------------------
// SRCM: 0 = src is bf16 activations as-is
//       1 = src is (max,min) pooled raw-y pair + prev BN (select-by-sign)+relu
//       2 = src is raw y + prev BN + relu
// OUTM: 0 = store raw y [b][W][COUT] + stats
//       1 = store pooled (max,min) of raw y [b][W/4][COUT] x2 + stats
template<int CIN, int COUT, int KK, int PAD, int DT, int NP, int S, int CT, int ST,
         int SRCM, int OUTM>
__global__ __launch_bounds__(256)
void conv_mfma2(const unsigned short* __restrict__ xA, const unsigned short* __restrict__ xB,
                const float* __restrict__ pscale, const float* __restrict__ pshift,
                const unsigned short* __restrict__ wpack, const float* __restrict__ bias,
                unsigned short* __restrict__ outA, unsigned short* __restrict__ outB,
                float* __restrict__ partials, int W)
{
    constexpr int CHUNK = 4 * ST * 16;
    constexpr int ROWB = CIN * 2 + 16;
    constexpr int ROWS = CHUNK + KK + (DT - 1) + 1;
    constexpr int DPR = CIN / 2;
    __shared__ __align__(16) unsigned char lx[ROWS * ROWB];
    __shared__ float sred[4][CT][4][4];
    __shared__ float ssred[4][CT][4][4];
    __shared__ float scb[(SRCM > 0) ? CIN : 1];
    __shared__ float shb[(SRCM > 0) ? CIN : 1];

    const int tid = threadIdx.x;
    const int ntile = W / CHUNK;
    const int b = blockIdx.x / ntile;
    const int tile = blockIdx.x % ntile;
    const int w0 = tile * CHUNK;

    if (SRCM > 0) {
        if (tid < CIN) {
            scb[tid] = pscale[(b >> 8) * CIN + tid];
            shb[tid] = pshift[(b >> 8) * CIN + tid];
        }
        __syncthreads();
    }

    for (int d = tid; d < ROWS * DPR; d += 256) {
        const int row = d / DPR;
        const int col = d % DPR;
        const int gw = w0 - PAD + row;
        unsigned v = 0;
        if (gw >= 0 && gw < W) {
            const long long src = ((long long)b * W + gw) * CIN + col * 2;
            if (SRCM == 0) {
                v = *(const unsigned*)(xA + src);
            } else {
                const unsigned va = *(const unsigned*)(xA + src);
                const float sc0 = scb[col * 2], sh0 = shb[col * 2];
                const float sc1 = scb[col * 2 + 1], sh1 = shb[col * 2 + 1];
                float f0, f1;
                if (SRCM == 1) {
                    const unsigned vb = *(const unsigned*)(xB + src);
                    f0 = fmaxf(fmaf(sc0, (sc0 > 0.f) ? bflo(va) : bflo(vb), sh0), 0.f);
                    f1 = fmaxf(fmaf(sc1, (sc1 > 0.f) ? bfhi(va) : bfhi(vb), sh1), 0.f);
                } else {
                    f0 = fmaxf(fmaf(sc0, bflo(va), sh0), 0.f);
                    f1 = fmaxf(fmaf(sc1, bfhi(va), sh1), 0.f);
                }
                v = (unsigned)f2bf(f0) | ((unsigned)f2bf(f1) << 16);
            }
        }
        *(unsigned*)(lx + row * ROWB + col * 4) = v;
    }
    __syncthreads();

    const int lane = tid & 63, wave = tid >> 6;
    const int n = lane & 15, kq = lane >> 4;
    int rowbase, cbyte;
    if (DT == 2) { rowbase = wave * ST * 16 + n + (kq >> 1); cbyte = (kq & 1) * 16; }
    else         { rowbase = wave * ST * 16 + n;             cbyte = kq * 16; }

    f32x4 acc[ST][CT];
#pragma unroll
    for (int st = 0; st < ST; ++st)
#pragma unroll
        for (int ct = 0; ct < CT; ++ct) { acc[st][ct][0]=0.f; acc[st][ct][1]=0.f; acc[st][ct][2]=0.f; acc[st][ct][3]=0.f; }

#pragma unroll
    for (int p = 0; p < NP; ++p) {
#pragma unroll
        for (int s = 0; s < S; ++s) {
            bf16x8 a[CT];
#pragma unroll
            for (int ct = 0; ct < CT; ++ct)
                a[ct] = *(const bf16x8*)(wpack + (((long long)(p * S + s) * CT + ct) * 64 + lane) * 8);
#pragma unroll
            for (int st = 0; st < ST; ++st) {
                const int r = rowbase + st * 16 + p * DT;
                const bf16x8 bf = *(const bf16x8*)(lx + r * ROWB + cbyte + s * 64);
#pragma unroll
                for (int ct = 0; ct < CT; ++ct)
                    acc[st][ct] = __builtin_amdgcn_mfma_f32_16x16x32_bf16(a[ct], bf, acc[st][ct], 0, 0, 0);
            }
        }
    }

    // epilogue: stats (+ y or pooled minmax store)
    float s_[CT][4], ss_[CT][4];
#pragma unroll
    for (int ct = 0; ct < CT; ++ct)
#pragma unroll
        for (int e = 0; e < 4; ++e) { s_[ct][e] = 0.f; ss_[ct][e] = 0.f; }

#pragma unroll
    for (int st = 0; st < ST; ++st) {
        const int w = w0 + wave * ST * 16 + st * 16 + n;
#pragma unroll
        for (int ct = 0; ct < CT; ++ct) {
            const float* bp = bias + ct * 16 + kq * 4;
            float v[4];
#pragma unroll
            for (int e = 0; e < 4; ++e) {
                v[e] = acc[st][ct][e] + bp[e];
                s_[ct][e] += v[e];
                ss_[ct][e] += v[e] * v[e];
            }
            if (OUTM == 0) {
                uint2 pk;
                pk.x = (unsigned)f2bf(v[0]) | ((unsigned)f2bf(v[1]) << 16);
                pk.y = (unsigned)f2bf(v[2]) | ((unsigned)f2bf(v[3]) << 16);
                *(uint2*)(outA + ((long long)b * W + w) * COUT + ct * 16 + kq * 4) = pk;
            } else {
                float mx[4], mn[4];
#pragma unroll
                for (int e = 0; e < 4; ++e) {
                    mx[e] = v[e]; mn[e] = v[e];
                    mx[e] = fmaxf(mx[e], __shfl_xor(mx[e], 1, 64));
                    mx[e] = fmaxf(mx[e], __shfl_xor(mx[e], 2, 64));
                    mn[e] = fminf(mn[e], __shfl_xor(mn[e], 1, 64));
                    mn[e] = fminf(mn[e], __shfl_xor(mn[e], 2, 64));
                }
                if ((n & 3) == 0) {
                    const long long o = ((long long)b * (W >> 2) + (w >> 2)) * COUT + ct * 16 + kq * 4;
                    uint2 pa, pb;
                    pa.x = (unsigned)f2bf(mx[0]) | ((unsigned)f2bf(mx[1]) << 16);
                    pa.y = (unsigned)f2bf(mx[2]) | ((unsigned)f2bf(mx[3]) << 16);
                    pb.x = (unsigned)f2bf(mn[0]) | ((unsigned)f2bf(mn[1]) << 16);
                    pb.y = (unsigned)f2bf(mn[2]) | ((unsigned)f2bf(mn[3]) << 16);
                    *(uint2*)(outA + o) = pa;
                    *(uint2*)(outB + o) = pb;
                }
            }
        }
    }
#pragma unroll
    for (int m = 1; m < 16; m <<= 1) {
#pragma unroll
        for (int ct = 0; ct < CT; ++ct)
#pragma unroll
            for (int e = 0; e < 4; ++e) {
                s_[ct][e]  += __shfl_xor(s_[ct][e], m, 64);
                ss_[ct][e] += __shfl_xor(ss_[ct][e], m, 64);
            }
    }
    if (n == 0) {
#pragma unroll
        for (int ct = 0; ct < CT; ++ct)
#pragma unroll
            for (int e = 0; e < 4; ++e) {
                sred[wave][ct][kq][e] = s_[ct][e];
                ssred[wave][ct][kq][e] = ss_[ct][e];
            }
    }
    __syncthreads();
    if (tid < COUT) {
        const int ct = tid >> 4, q = (tid >> 2) & 3, e = tid & 3;
        float sumv = 0.f, sumsq = 0.f;
#pragma unroll
        for (int wv = 0; wv < 4; ++wv) { sumv += sred[wv][ct][q][e]; sumsq += ssred[wv][ct][q][e]; }
        partials[((long long)blockIdx.x * COUT + tid) * 2 + 0] = sumv;
        partials[((long long)blockIdx.x * COUT + tid) * 2 + 1] = sumsq;
    }
}

// ---------------- fused tail: adapool (blocks 0..511) + srow (512..1023) ----
__global__ void tail_pool_srow(const unsigned short* __restrict__ yT2b,
                               const float* __restrict__ scT2, const float* __restrict__ shT2,
                               const unsigned short* __restrict__ yMax3,
                               const unsigned short* __restrict__ yMin3,
                               const float* __restrict__ scS3, const float* __restrict__ shS3,
                               float* __restrict__ kk, float* __restrict__ Sv)
{
    __shared__ float hb[128][64];
    const int tid = threadIdx.x;
    if (blockIdx.x < BSZ2) {
        // ---- BN+ReLU + adaptive-avg-pool(5) from raw y_t2 ----
        const int b = blockIdx.x;
        const uint2* yd = (const uint2*)(yT2b + (long long)b * 128 * 64);
        for (int i = tid; i < 128 * 16; i += 256) {
            const int w = i >> 4, c4 = (i & 15) * 4;
            const float* scp = scT2 + (b >> 8) * 64 + c4;
            const float* shp = shT2 + (b >> 8) * 64 + c4;
            const uint2 v = yd[i];
            hb[w][c4 + 0] = fmaxf(fmaf(scp[0], bflo(v.x), shp[0]), 0.f);
            hb[w][c4 + 1] = fmaxf(fmaf(scp[1], bfhi(v.x), shp[1]), 0.f);
            hb[w][c4 + 2] = fmaxf(fmaf(scp[2], bflo(v.y), shp[2]), 0.f);
            hb[w][c4 + 3] = fmaxf(fmaf(scp[3], bfhi(v.y), shp[3]), 0.f);
        }
        __syncthreads();
        const int bs[5] = {0, 25, 51, 76, 102};
        const int be[5] = {26, 52, 77, 103, 128};
        for (int o = tid; o < 320; o += 256) {
            const int cc = o & 63, bin = o >> 6;
            float acc = 0.f;
            for (int w = bs[bin]; w < be[bin]; ++w) acc += hb[w][cc];
            kk[((long long)b * 64 + cc) * 5 + bin] = acc / (float)(be[bin] - bs[bin]);
        }
    } else {
        // ---- h = BN-select+ReLU from stage3 minmax; center+norm -> Sv ----
        __shared__ float red[4][64];
        __shared__ float mrow[64];
        const int b = blockIdx.x - BSZ2;
        const int c = tid & 63, grp = tid >> 6;
        const uint2* ya = (const uint2*)(yMax3 + (long long)b * 128 * 64);
        const uint2* yb = (const uint2*)(yMin3 + (long long)b * 128 * 64);
        for (int i = tid; i < 128 * 16; i += 256) {
            const int w = i >> 4, c4 = (i & 15) * 4;
            const float* scp = scS3 + (b >> 8) * 64 + c4;
            const float* shp = shS3 + (b >> 8) * 64 + c4;
            const uint2 va = ya[i], vb = yb[i];
            hb[w][c4 + 0] = fmaxf(fmaf(scp[0], (scp[0] > 0.f) ? bflo(va.x) : bflo(vb.x), shp[0]), 0.f);
            hb[w][c4 + 1] = fmaxf(fmaf(scp[1], (scp[1] > 0.f) ? bfhi(va.x) : bfhi(vb.x), shp[1]), 0.f);
            hb[w][c4 + 2] = fmaxf(fmaf(scp[2], (scp[2] > 0.f) ? bflo(va.y) : bflo(vb.y), shp[2]), 0.f);
            hb[w][c4 + 3] = fmaxf(fmaf(scp[3], (scp[3] > 0.f) ? bfhi(va.y) : bfhi(vb.y), shp[3]), 0.f);
        }
        __syncthreads();
        float s = 0.f;
        for (int w = grp * 32; w < grp * 32 + 32; ++w) s += hb[w][c];
        red[grp][c] = s;
        __syncthreads();
        if (tid < 64) mrow[tid] = (red[0][tid] + red[1][tid] + red[2][tid] + red[3][tid]) / 128.f;
        __syncthreads();
        const float m = mrow[c];
        float q = 0.f;
        for (int w = grp * 32; w < grp * 32 + 32; ++w) { const float d = hb[w][c] - m; q += d * d; }
        red[grp][c] = q;
        __syncthreads();
        if (tid < 64) {
            const float n2 = red[0][tid] + red[1][tid] + red[2][tid] + red[3][tid];
            const float n = fmaxf(sqrtf(n2), 1e-12f);
            const float m0 = mrow[tid];
            const float h0 = (hb[0][tid] - m0) / n, h1 = (hb[1][tid] - m0) / n;
            const float hN1 = (hb[127][tid] - m0) / n, hN2 = (hb[126][tid] - m0) / n;
            float* o = Sv + ((long long)b * 64 + tid) * 5;
            o[0] = -(hN2 + hN1); o[1] = -hN1; o[2] = 0.f; o[3] = -h0; o[4] = -(h0 + h1);
        }
    }
}

// merged: blocks [0,128) = flatnorm (wave-per-row), [128,256) = knorm
__global__ void norm_both(const float* __restrict__ kk, float* __restrict__ kn,
                          float* __restrict__ ab)
{
    if (blockIdx.x < 128) {
        const int wave = threadIdx.x >> 6, lane = threadIdx.x & 63;
        const int row = blockIdx.x * 4 + wave;
        const float* p = kk + (long long)row * 320;
        float n2 = 0.f;
        for (int d = lane; d < 320; d += 64) n2 += p[d] * p[d];
#pragma unroll
        for (int m = 1; m < 64; m <<= 1) n2 += __shfl_xor(n2, m, 64);
        const float n = fmaxf(sqrtf(n2), 1e-12f);
        float* o = ab + (long long)row * 320;
        for (int d = lane; d < 320; d += 64) o[d] = p[d] / n;
    } else {
        const int i = (blockIdx.x - 128) * NTHR + threadIdx.x;
        const float* p = kk + (long long)i * 5;
        float m = 0.f;
        for (int t = 0; t < 5; ++t) m += p[t];
        m *= 0.2f;
        float v[5]; float n2 = 0.f;
        for (int t = 0; t < 5; ++t) { v[t] = p[t] - m; n2 += v[t] * v[t]; }
        float n = fmaxf(sqrtf(n2), 1e-12f);
        for (int t = 0; t < 5; ++t) kn[(long long)i * 5 + t] = v[t] / n;
    }
}

// fused similarity + per-row log-softmax diag. grid (256, 3), block 256.
__global__ void simdot_nce(const float* __restrict__ kn, const float* __restrict__ Sv,
                           const float* __restrict__ ab, float* __restrict__ lp)
{
    const int j = threadIdx.x;
    const int i = blockIdx.x;
    const int z = blockIdx.y;
    const float* a;
    const float* b;
    float coef;
    if (z == 0)      { a = kn + (long long)i * 320;         b = Sv + (long long)(256 + j) * 320; coef = 10.f / 128.f; }
    else if (z == 1) { a = kn + (long long)(256 + i) * 320; b = Sv + (long long)j * 320;         coef = 10.f / 128.f; }
    else             { a = ab + (long long)i * 320;         b = ab + (long long)(256 + j) * 320; coef = 10.f; }
    float acc = 0.f;
    for (int d = 0; d < 320; ++d) acc += a[d] * b[d];
    const float v = acc * coef;

    __shared__ float red[NTHR];
    __shared__ float sdiag;
    if (j == i) sdiag = v;
    red[j] = v;
    __syncthreads();
    for (int off = NTHR / 2; off > 0; off >>= 1) {
        if (j < off) red[j] = fmaxf(red[j], red[j + off]);
        __syncthreads();
    }
    const float mx = red[0];
    __syncthreads();
    red[j] = expf(v - mx);
    __syncthreads();
    for (int off = NTHR / 2; off > 0; off >>= 1) {
        if (j < off) red[j] += red[j + off];
        __syncthreads();
    }
    if (j == 0) lp[z * 256 + i] = sdiag - (mx + logf(red[0]));
}

// reduce lp -> final loss scalar
__global__ void final3(const float* __restrict__ lp, float* __restrict__ out)
{
    __shared__ float red[NTHR];
    const int tid = threadIdx.x;
    float l[3];
    for (int z = 0; z < 3; ++z) {
        red[tid] = lp[z * 256 + tid];
        __syncthreads();
        for (int off = NTHR / 2; off > 0; off >>= 1) {
            if (tid < off) red[tid] += red[tid + off];
            __syncthreads();
        }
        l[z] = red[0];
        __syncthreads();
    }
    if (tid == 0)
        out[0] = 0.5f * (-l[0] / 256.f - l[1] / 256.f) + 0.5f * (-l[2] / 256.f);
}

// ---------------------------------------------------------------------------

extern "C" void kernel_launch(void* const* d_in, const int* in_sizes, int n_in,
                              void* d_out, int out_size, void* d_ws, size_t ws_size,
                              hipStream_t stream)
{
    const float* x1  = (const float*)d_in[0];
    const float* x2  = (const float*)d_in[1];
    const float* w1  = (const float*)d_in[2];
    const float* b1  = (const float*)d_in[3];
    const float* g1  = (const float*)d_in[4];
    const float* be1 = (const float*)d_in[5];
    const float* w2  = (const float*)d_in[6];
    const float* b2  = (const float*)d_in[7];
    const float* g2  = (const float*)d_in[8];
    const float* be2 = (const float*)d_in[9];
    const float* w3  = (const float*)d_in[10];
    const float* b3  = (const float*)d_in[11];
    const float* g3  = (const float*)d_in[12];
    const float* be3 = (const float*)d_in[13];
    const float* tw1 = (const float*)d_in[14];
    const float* tb1 = (const float*)d_in[15];
    const float* tg1 = (const float*)d_in[16];
    const float* tbe1= (const float*)d_in[17];
    const float* tw2 = (const float*)d_in[18];
    const float* tb2 = (const float*)d_in[19];
    const float* tg2 = (const float*)d_in[20];
    const float* tbe2= (const float*)d_in[21];
    float* out = (float*)d_out;

    char* ws = (char*)d_ws;
    size_t off = 0;
    auto alloc = [&](size_t bytes) -> void* {
        off = (off + 255) & ~(size_t)255;
        void* p = ws + off;
        off += bytes;
        return p;
    };
    typedef unsigned short u16;
    u16* xT2   = (u16*)alloc((size_t)BSZ2 * 2048 * 16 * 2);  // stage1 out   33.6MB
    u16* yMax2 = (u16*)alloc((size_t)BSZ2 * 512 * 32 * 2);   // 16.8MB
    u16* yMin2 = (u16*)alloc((size_t)BSZ2 * 512 * 32 * 2);   // 16.8MB
    u16* yMax3 = (u16*)alloc((size_t)BSZ2 * 128 * 64 * 2);   //  8.4MB
    u16* yMin3 = (u16*)alloc((size_t)BSZ2 * 128 * 64 * 2);   //  8.4MB
    u16* yT1   = (u16*)alloc((size_t)BSZ2 * 128 * 64 * 2);   //  8.4MB
    u16* yT2b  = (u16*)alloc((size_t)BSZ2 * 128 * 64 * 2);   //  8.4MB
    u16* wp1  = (u16*)alloc((size_t)512 * 2);
    u16* wp2  = (u16*)alloc((size_t)9 * 1 * 2 * 512 * 2);
    u16* wp3  = (u16*)alloc((size_t)17 * 1 * 4 * 512 * 2);
    u16* wpt1 = (u16*)alloc((size_t)5 * 2 * 4 * 512 * 2);
    u16* wpt2 = (u16*)alloc((size_t)3 * 2 * 4 * 512 * 2);
    float* kk   = (float*)alloc((size_t)BSZ2 * 320 * 4);
    float* kn   = (float*)alloc((size_t)BSZ2 * 320 * 4);
    float* ab   = (float*)alloc((size_t)BSZ2 * 320 * 4);
    float* Sv   = (float*)alloc((size_t)BSZ2 * 320 * 4);
    float* lp   = (float*)alloc((size_t)3 * 256 * 4);
    float* partials = (float*)alloc((size_t)16384 * 16 * 2 * 4);  // 2 MB
    float* scales = (float*)alloc((size_t)5 * 128 * 4);           // per-stage [2][C]
    float* shifts = (float*)alloc((size_t)5 * 128 * 4);
    float* sc1 = scales + 0 * 128, * sh1 = shifts + 0 * 128;
    float* sc2 = scales + 1 * 128, * sh2 = shifts + 1 * 128;
    float* sc3 = scales + 2 * 128, * sh3 = shifts + 2 * 128;
    float* sct1 = scales + 3 * 128, * sht1 = shifts + 3 * 128;
    float* sct2 = scales + 4 * 128, * sht2 = shifts + 4 * 128;

    build_all_wpacks<<<303, NTHR, 0, stream>>>(w1, w2, w3, tw1, tw2, wp1, wp2, wp3, wpt1, wpt2);

    // ---- stage 1: MFMA conv (1->16), stats -> finalize -> apply(pool) ----
    {
        const int nblk = BSZ2 * (8192 / 512);
        conv1_mfma<8, 0><<<nblk, 256, 0, stream>>>(x1, x2, wp1, b1, nullptr, nullptr, nullptr, partials);
        dim3 fg(16, 2);
        finalize2<16><<<fg, NTHR, 0, stream>>>(partials, nblk / 2, 1.f / ((float)256 * 8192), g1, be1, sc1, sh1);
        conv1_mfma<8, 1><<<nblk, 256, 0, stream>>>(x1, x2, wp1, b1, sc1, sh1, xT2, nullptr);
    }
    // ---- stage 2: conv + stats + pooled minmax ----
    {
        const int nblk = BSZ2 * (2048 / 256);
        conv_mfma2<16,32,17,8,2,9,1,2,4, 0,1><<<nblk, 256, 0, stream>>>(
            xT2, nullptr, nullptr, nullptr, wp2, b2, yMax2, yMin2, partials, 2048);
        dim3 fg(32, 2);
        finalize2<32><<<fg, NTHR, 0, stream>>>(partials, nblk / 2, 1.f / ((float)256 * 2048), g2, be2, sc2, sh2);
    }
    // ---- stage 3: stage-from-minmax(BN2) + conv + stats + pooled minmax ----
    {
        const int nblk = BSZ2 * (512 / 256);
        conv_mfma2<32,64,17,8,1,17,1,4,4, 1,1><<<nblk, 256, 0, stream>>>(
            yMax2, yMin2, sc2, sh2, wp3, b3, yMax3, yMin3, partials, 512);
        dim3 fg(64, 2);
        finalize2<64><<<fg, NTHR, 0, stream>>>(partials, nblk / 2, 1.f / ((float)256 * 512), g3, be3, sc3, sh3);
    }
    // ---- template stage 1: stage-from-minmax(BN3) + conv + stats + y ----
    {
        conv_mfma2<64,64,5,2,1,5,2,4,2, 1,0><<<BSZ2, 256, 0, stream>>>(
            yMax3, yMin3, sc3, sh3, wpt1, tb1, yT1, nullptr, partials, 128);
        dim3 fg(64, 2);
        finalize2<64><<<fg, NTHR, 0, stream>>>(partials, 256, 1.f / ((float)256 * 128), tg1, tbe1, sct1, sht1);
    }
    // ---- template stage 2: stage-from-y(BNt1) + conv + stats + y ----
    {
        conv_mfma2<64,64,3,1,1,3,2,4,2, 2,0><<<BSZ2, 256, 0, stream>>>(
            yT1, nullptr, sct1, sht1, wpt2, tb2, yT2b, nullptr, partials, 128);
        dim3 fg(64, 2);
        finalize2<64><<<fg, NTHR, 0, stream>>>(partials, 256, 1.f / ((float)256 * 128), tg2, tbe2, sct2, sht2);
    }

    // ---- tail: adapool(yT2b) + srow(minmax3), fused ----
    tail_pool_srow<<<2 * BSZ2, 256, 0, stream>>>(yT2b, sct2, sht2, yMax3, yMin3, sc3, sh3, kk, Sv);
    norm_both<<<256, NTHR, 0, stream>>>(kk, kn, ab);
    dim3 sg(256, 3);
    simdot_nce<<<sg, NTHR, 0, stream>>>(kn, Sv, ab, lp);
    final3<<<1, NTHR, 0, stream>>>(lp, out);
}

// Round 11
// 202.218 us; speedup vs baseline: 1.4878x; 1.2859x over previous
//
#include <hip/hip_runtime.h>
#include <hip/hip_bf16.h>
#include <math.h>

// ---------------------------------------------------------------------------
// TCCL model forward. Round 10:
//  - MFMA operand swap: D = mfma(x_frag, w_frag) -> D[w][co] with co=lane&15,
//    w=kq*4+e. Fragment data/staging/wpack UNCHANGED (both A and B layouts key
//    their free index off lane&15); only arg order + epilogue indexing change.
//    => maxpool/minpool over w is REGISTER-LOCAL (max3, no shuffles),
//       stats reduce is 2 shfl steps (was 4), stores per-lane coalesced u16.
//    (R9 post-mortem: stage2 epilogue was ~850 VALU ops/wave vs 350 cyc MFMA)
//  - structure, buffers, launches identical to R9 (passing).
// ---------------------------------------------------------------------------

#define BSZ2 512          // combined batch (x1 ++ x2)
#define NTHR 256

typedef __attribute__((ext_vector_type(8))) short bf16x8;
typedef __attribute__((ext_vector_type(4))) float f32x4;

static inline int ceil_divll(long long a, int b) { return (int)((a + b - 1) / b); }

__device__ __forceinline__ unsigned short f2bf(float f) {
    unsigned u = __float_as_uint(f);
    u = (u + 0x7FFFu + ((u >> 16) & 1u)) >> 16;
    return (unsigned short)u;
}
__device__ __forceinline__ float bf2f(unsigned short h) {
    return __uint_as_float(((unsigned)h) << 16);
}
__device__ __forceinline__ float bflo(unsigned u) { return __uint_as_float(u << 16); }
__device__ __forceinline__ float bfhi(unsigned u) { return __uint_as_float(u & 0xFFFF0000u); }

// ---------------- stage 1 MFMA conv (Cin=1, K=17 padded to 32) --------------
// swapped operands: D[w][co], co = lane&15, w = kq*4+e (register axis pool!)
// MODE 0 = stats partials; MODE 1 = BN+ReLU+maxpool4 -> bf16 [b][wp][16]
template<int WT, int MODE>
__global__ __launch_bounds__(256)
void conv1_mfma(const float* __restrict__ x1, const float* __restrict__ x2,
                const unsigned short* __restrict__ wpack1, const float* __restrict__ bias,
                const float* __restrict__ scale, const float* __restrict__ shift,
                unsigned short* __restrict__ out, float* __restrict__ partials)
{
    constexpr int W = 8192;
    constexpr int CHUNK = 4 * WT * 16;
    __shared__ float xs[CHUNK + 32];
    __shared__ float sred[(MODE == 0) ? 4 : 1][16];
    __shared__ float ssred[(MODE == 0) ? 4 : 1][16];

    const int tid = threadIdx.x;
    const int ntile = W / CHUNK;
    const int b = blockIdx.x / ntile;
    const int w0 = (blockIdx.x % ntile) * CHUNK;
    const float* xrow = (b < 256) ? x1 + (long long)b * W : x2 + (long long)(b - 256) * W;

    for (int i = tid; i < CHUNK + 32; i += 256) {
        const int gw = w0 - 8 + i;
        xs[i] = (gw >= 0 && gw < W) ? xrow[gw] : 0.f;
    }
    __syncthreads();

    const int lane = tid & 63, wave = tid >> 6;
    const int n = lane & 15, kq = lane >> 4;
    const bf16x8 a = *(const bf16x8*)(wpack1 + lane * 8);   // weights: co=n, k=kq*8+j

    f32x4 acc[WT];
#pragma unroll
    for (int wt = 0; wt < WT; ++wt) { acc[wt][0]=0.f; acc[wt][1]=0.f; acc[wt][2]=0.f; acc[wt][3]=0.f; }

    const int base0 = wave * WT * 16 + n + kq * 8;          // x frag: row w=n, k=kq*8+j
#pragma unroll
    for (int wt = 0; wt < WT; ++wt) {
        bf16x8 bv;
#pragma unroll
        for (int j = 0; j < 8; ++j) {
            __hip_bfloat16 h = __float2bfloat16(xs[base0 + wt * 16 + j]);
            bv[j] = *reinterpret_cast<short*>(&h);
        }
        acc[wt] = __builtin_amdgcn_mfma_f32_16x16x32_bf16(bv, a, acc[wt], 0, 0, 0);  // D[w][co]
    }

    if (MODE == 0) {
        const float bi = bias[n];
        float s_ = 0.f, ss_ = 0.f;
#pragma unroll
        for (int wt = 0; wt < WT; ++wt)
#pragma unroll
            for (int e = 0; e < 4; ++e) {
                const float y = acc[wt][e] + bi;
                s_ += y; ss_ += y * y;
            }
        s_  += __shfl_xor(s_, 16, 64);  s_  += __shfl_xor(s_, 32, 64);
        ss_ += __shfl_xor(ss_, 16, 64); ss_ += __shfl_xor(ss_, 32, 64);
        if (lane < 16) { sred[wave][n] = s_; ssred[wave][n] = ss_; }
        __syncthreads();
        if (tid < 16) {
            float sumv = 0.f, sumsq = 0.f;
#pragma unroll
            for (int wv = 0; wv < 4; ++wv) { sumv += sred[wv][tid]; sumsq += ssred[wv][tid]; }
            partials[((long long)blockIdx.x * 16 + tid) * 2 + 0] = sumv;
            partials[((long long)blockIdx.x * 16 + tid) * 2 + 1] = sumsq;
        }
    } else {
        const int half = b >> 8;
        const float bi = bias[n];
        const float scv = scale[half * 16 + n];
        const float shv = shift[half * 16 + n];
#pragma unroll
        for (int wt = 0; wt < WT; ++wt) {
            float v[4];
#pragma unroll
            for (int e = 0; e < 4; ++e) v[e] = fmaf(scv, acc[wt][e] + bi, shv);
            const float mx = fmaxf(fmaxf(fmaxf(v[0], v[1]), fmaxf(v[2], v[3])), 0.f);
            const int wp = (w0 >> 2) + wave * WT * 4 + wt * 4 + kq;
            out[((long long)b * 2048 + wp) * 16 + n] = f2bf(mx);
        }
    }
}

// per-channel, per-half finalize. grid (COUT, 2).
template<int COUT>
__global__ void finalize2(const float* __restrict__ partials, int nblk_half, float invN,
                          const float* __restrict__ g, const float* __restrict__ be,
                          float* __restrict__ scale, float* __restrict__ shift)
{
    const int co = blockIdx.x;
    const int half = blockIdx.y;
    const float* P = partials + (size_t)half * nblk_half * COUT * 2;
    float s = 0.f, ss = 0.f;
    for (int i = threadIdx.x; i < nblk_half; i += NTHR) {
        s  += P[((long long)i * COUT + co) * 2 + 0];
        ss += P[((long long)i * COUT + co) * 2 + 1];
    }
    __shared__ float red[NTHR][2];
    red[threadIdx.x][0] = s; red[threadIdx.x][1] = ss;
    __syncthreads();
    for (int off = NTHR / 2; off > 0; off >>= 1) {
        if ((int)threadIdx.x < off) {
            red[threadIdx.x][0] += red[threadIdx.x + off][0];
            red[threadIdx.x][1] += red[threadIdx.x + off][1];
        }
        __syncthreads();
    }
    if (threadIdx.x == 0) {
        const float m = red[0][0] * invN;
        const float v = red[0][1] * invN - m * m;
        const float inv = rsqrtf(v + 1e-5f);
        const float sc = g[co] * inv;
        scale[half * COUT + co] = sc;
        shift[half * COUT + co] = be[co] - sc * m;
    }
}

// ---------------- weight prepacks (one launch) ------------------------------
template<int CIN, int KK, int DT, int NP, int S, int CT>
__device__ __forceinline__ void pack_one(int idx, const float* __restrict__ wgt,
                                         unsigned short* __restrict__ wp)
{
    const int j = idx & 7;
    const int l = (idx >> 3) & 63;
    int rest = idx >> 9;
    const int ct = rest % CT; rest /= CT;
    const int s = rest % S;
    const int p = rest / S;
    const int co = ct * 16 + (l & 15);
    const int k = (l >> 4) * 8 + j;
    int ci, t;
    if (DT == 2) { ci = k & (CIN - 1); t = p * 2 + (k >> 4); }
    else         { ci = s * 32 + k;    t = p; }
    float v = (t < KK) ? wgt[((long long)co * CIN + ci) * KK + t] : 0.f;
    wp[idx] = f2bf(v);
}

__global__ void build_all_wpacks(const float* __restrict__ w1, const float* __restrict__ w2,
                                 const float* __restrict__ w3,
                                 const float* __restrict__ tw1, const float* __restrict__ tw2,
                                 unsigned short* __restrict__ wp1,
                                 unsigned short* __restrict__ wp2, unsigned short* __restrict__ wp3,
                                 unsigned short* __restrict__ wpt1, unsigned short* __restrict__ wpt2)
{
    const int idx = blockIdx.x * NTHR + threadIdx.x;
    const int n1 = 512;
    const int n2 = 9 * 1 * 2 * 512;
    const int n3 = 17 * 1 * 4 * 512;
    const int nt1 = 5 * 2 * 4 * 512;
    const int nt2 = 3 * 2 * 4 * 512;
    if (idx < n1) {
        const int j = idx & 7, l = idx >> 3;
        const int co = l & 15, k = (l >> 4) * 8 + j;
        wp1[idx] = f2bf((k < 17) ? w1[co * 17 + k] : 0.f);
    }
    else if (idx < n1 + n2) pack_one<16, 17, 2, 9, 1, 2>(idx - n1, w2, wp2);
    else if (idx < n1 + n2 + n3) pack_one<32, 17, 1, 17, 1, 4>(idx - n1 - n2, w3, wp3);
    else if (idx < n1 + n2 + n3 + nt1) pack_one<64, 5, 1, 5, 2, 4>(idx - n1 - n2 - n3, tw1, wpt1);
    else if (idx < n1 + n2 + n3 + nt1 + nt2) pack_one<64, 3, 1, 3, 2, 4>(idx - n1 - n2 - n3 - nt1, tw2, wpt2);
}

// ---------------- MFMA conv, generalized (swapped operands) -----------------
// D[w][co]: co = ct*16 + (lane&15), w = w0 + wave*ST*16 + st*16 + kq*4 + e
// SRCM: 0 = src bf16 as-is; 1 = (max,min) pair + prev BN select + relu;
//       2 = raw y + prev BN + relu
// OUTM: 0 = store raw y [b][W][COUT] + stats
//       1 = store pooled (max,min) of raw y [b][W/4][COUT] x2 + stats
template<int CIN, int COUT, int KK, int PAD, int DT, int NP, int S, int CT, int ST,
         int SRCM, int OUTM>
__global__ __launch_bounds__(256)
void conv_mfma2(const unsigned short* __restrict__ xA, const unsigned short* __restrict__ xB,
                const float* __restrict__ pscale, const float* __restrict__ pshift,
                const unsigned short* __restrict__ wpack, const float* __restrict__ bias,
                unsigned short* __restrict__ outA, unsigned short* __restrict__ outB,
                float* __restrict__ partials, int W)
{
    constexpr int CHUNK = 4 * ST * 16;
    constexpr int ROWB = CIN * 2 + 16;
    constexpr int ROWS = CHUNK + KK + (DT - 1) + 1;
    constexpr int DPR = CIN / 2;
    __shared__ __align__(16) unsigned char lx[ROWS * ROWB];
    __shared__ float sred[4][CT][16];
    __shared__ float ssred[4][CT][16];
    __shared__ float scb[(SRCM > 0) ? CIN : 1];
    __shared__ float shb[(SRCM > 0) ? CIN : 1];

    const int tid = threadIdx.x;
    const int ntile = W / CHUNK;
    const int b = blockIdx.x / ntile;
    const int tile = blockIdx.x % ntile;
    const int w0 = tile * CHUNK;

    if (SRCM > 0) {
        if (tid < CIN) {
            scb[tid] = pscale[(b >> 8) * CIN + tid];
            shb[tid] = pshift[(b >> 8) * CIN + tid];
        }
        __syncthreads();
    }

    for (int d = tid; d < ROWS * DPR; d += 256) {
        const int row = d / DPR;
        const int col = d % DPR;
        const int gw = w0 - PAD + row;
        unsigned v = 0;
        if (gw >= 0 && gw < W) {
            const long long src = ((long long)b * W + gw) * CIN + col * 2;
            if (SRCM == 0) {
                v = *(const unsigned*)(xA + src);
            } else {
                const unsigned va = *(const unsigned*)(xA + src);
                const float sc0 = scb[col * 2], sh0 = shb[col * 2];
                const float sc1 = scb[col * 2 + 1], sh1 = shb[col * 2 + 1];
                float f0, f1;
                if (SRCM == 1) {
                    const unsigned vb = *(const unsigned*)(xB + src);
                    f0 = fmaxf(fmaf(sc0, (sc0 > 0.f) ? bflo(va) : bflo(vb), sh0), 0.f);
                    f1 = fmaxf(fmaf(sc1, (sc1 > 0.f) ? bfhi(va) : bfhi(vb), sh1), 0.f);
                } else {
                    f0 = fmaxf(fmaf(sc0, bflo(va), sh0), 0.f);
                    f1 = fmaxf(fmaf(sc1, bfhi(va), sh1), 0.f);
                }
                v = (unsigned)f2bf(f0) | ((unsigned)f2bf(f1) << 16);
            }
        }
        *(unsigned*)(lx + row * ROWB + col * 4) = v;
    }
    __syncthreads();

    const int lane = tid & 63, wave = tid >> 6;
    const int n = lane & 15, kq = lane >> 4;
    int rowbase, cbyte;
    if (DT == 2) { rowbase = wave * ST * 16 + n + (kq >> 1); cbyte = (kq & 1) * 16; }
    else         { rowbase = wave * ST * 16 + n;             cbyte = kq * 16; }

    f32x4 acc[ST][CT];
#pragma unroll
    for (int st = 0; st < ST; ++st)
#pragma unroll
        for (int ct = 0; ct < CT; ++ct) { acc[st][ct][0]=0.f; acc[st][ct][1]=0.f; acc[st][ct][2]=0.f; acc[st][ct][3]=0.f; }

#pragma unroll
    for (int p = 0; p < NP; ++p) {
#pragma unroll
        for (int s = 0; s < S; ++s) {
            bf16x8 a[CT];
#pragma unroll
            for (int ct = 0; ct < CT; ++ct)
                a[ct] = *(const bf16x8*)(wpack + (((long long)(p * S + s) * CT + ct) * 64 + lane) * 8);
#pragma unroll
            for (int st = 0; st < ST; ++st) {
                const int r = rowbase + st * 16 + p * DT;
                const bf16x8 bf = *(const bf16x8*)(lx + r * ROWB + cbyte + s * 64);
#pragma unroll
                for (int ct = 0; ct < CT; ++ct)
                    acc[st][ct] = __builtin_amdgcn_mfma_f32_16x16x32_bf16(bf, a[ct], acc[st][ct], 0, 0, 0);
            }
        }
    }

    // epilogue: D[w][co] -> pool over register axis; per-lane scalar stores
    float s_[CT], ss_[CT];
#pragma unroll
    for (int ct = 0; ct < CT; ++ct) { s_[ct] = 0.f; ss_[ct] = 0.f; }

#pragma unroll
    for (int st = 0; st < ST; ++st) {
        const int wbase = w0 + wave * ST * 16 + st * 16 + kq * 4;
#pragma unroll
        for (int ct = 0; ct < CT; ++ct) {
            const float bi = bias[ct * 16 + n];
            float v[4];
#pragma unroll
            for (int e = 0; e < 4; ++e) {
                v[e] = acc[st][ct][e] + bi;
                s_[ct] += v[e];
                ss_[ct] += v[e] * v[e];
            }
            if (OUTM == 0) {
#pragma unroll
                for (int e = 0; e < 4; ++e)
                    outA[((long long)b * W + wbase + e) * COUT + ct * 16 + n] = f2bf(v[e]);
            } else {
                const float mx = fmaxf(fmaxf(v[0], v[1]), fmaxf(v[2], v[3]));
                const float mn = fminf(fminf(v[0], v[1]), fminf(v[2], v[3]));
                const long long o = ((long long)b * (W >> 2) + (wbase >> 2)) * COUT + ct * 16 + n;
                outA[o] = f2bf(mx);
                outB[o] = f2bf(mn);
            }
        }
    }
#pragma unroll
    for (int ct = 0; ct < CT; ++ct) {
        s_[ct]  += __shfl_xor(s_[ct], 16, 64);  s_[ct]  += __shfl_xor(s_[ct], 32, 64);
        ss_[ct] += __shfl_xor(ss_[ct], 16, 64); ss_[ct] += __shfl_xor(ss_[ct], 32, 64);
    }
    if (lane < 16) {
#pragma unroll
        for (int ct = 0; ct < CT; ++ct) { sred[wave][ct][n] = s_[ct]; ssred[wave][ct][n] = ss_[ct]; }
    }
    __syncthreads();
    if (tid < COUT) {
        const int ct = tid >> 4, nn = tid & 15;
        float sumv = 0.f, sumsq = 0.f;
#pragma unroll
        for (int wv = 0; wv < 4; ++wv) { sumv += sred[wv][ct][nn]; sumsq += ssred[wv][ct][nn]; }
        partials[((long long)blockIdx.x * COUT + tid) * 2 + 0] = sumv;
        partials[((long long)blockIdx.x * COUT + tid) * 2 + 1] = sumsq;
    }
}

// ---------------- fused tail: adapool (blocks 0..511) + srow (512..1023) ----
__global__ void tail_pool_srow(const unsigned short* __restrict__ yT2b,
                               const float* __restrict__ scT2, const float* __restrict__ shT2,
                               const unsigned short* __restrict__ yMax3,
                               const unsigned short* __restrict__ yMin3,
                               const float* __restrict__ scS3, const float* __restrict__ shS3,
                               float* __restrict__ kk, float* __restrict__ Sv)
{
    __shared__ float hb[128][64];
    const int tid = threadIdx.x;
    if (blockIdx.x < BSZ2) {
        const int b = blockIdx.x;
        const uint2* yd = (const uint2*)(yT2b + (long long)b * 128 * 64);
        for (int i = tid; i < 128 * 16; i += 256) {
            const int w = i >> 4, c4 = (i & 15) * 4;
            const float* scp = scT2 + (b >> 8) * 64 + c4;
            const float* shp = shT2 + (b >> 8) * 64 + c4;
            const uint2 v = yd[i];
            hb[w][c4 + 0] = fmaxf(fmaf(scp[0], bflo(v.x), shp[0]), 0.f);
            hb[w][c4 + 1] = fmaxf(fmaf(scp[1], bfhi(v.x), shp[1]), 0.f);
            hb[w][c4 + 2] = fmaxf(fmaf(scp[2], bflo(v.y), shp[2]), 0.f);
            hb[w][c4 + 3] = fmaxf(fmaf(scp[3], bfhi(v.y), shp[3]), 0.f);
        }
        __syncthreads();
        const int bs[5] = {0, 25, 51, 76, 102};
        const int be[5] = {26, 52, 77, 103, 128};
        for (int o = tid; o < 320; o += 256) {
            const int cc = o & 63, bin = o >> 6;
            float acc = 0.f;
            for (int w = bs[bin]; w < be[bin]; ++w) acc += hb[w][cc];
            kk[((long long)b * 64 + cc) * 5 + bin] = acc / (float)(be[bin] - bs[bin]);
        }
    } else {
        __shared__ float red[4][64];
        __shared__ float mrow[64];
        const int b = blockIdx.x - BSZ2;
        const int c = tid & 63, grp = tid >> 6;
        const uint2* ya = (const uint2*)(yMax3 + (long long)b * 128 * 64);
        const uint2* yb = (const uint2*)(yMin3 + (long long)b * 128 * 64);
        for (int i = tid; i < 128 * 16; i += 256) {
            const int w = i >> 4, c4 = (i & 15) * 4;
            const float* scp = scS3 + (b >> 8) * 64 + c4;
            const float* shp = shS3 + (b >> 8) * 64 + c4;
            const uint2 va = ya[i], vb = yb[i];
            hb[w][c4 + 0] = fmaxf(fmaf(scp[0], (scp[0] > 0.f) ? bflo(va.x) : bflo(vb.x), shp[0]), 0.f);
            hb[w][c4 + 1] = fmaxf(fmaf(scp[1], (scp[1] > 0.f) ? bfhi(va.x) : bfhi(vb.x), shp[1]), 0.f);
            hb[w][c4 + 2] = fmaxf(fmaf(scp[2], (scp[2] > 0.f) ? bflo(va.y) : bflo(vb.y), shp[2]), 0.f);
            hb[w][c4 + 3] = fmaxf(fmaf(scp[3], (scp[3] > 0.f) ? bfhi(va.y) : bfhi(vb.y), shp[3]), 0.f);
        }
        __syncthreads();
        float s = 0.f;
        for (int w = grp * 32; w < grp * 32 + 32; ++w) s += hb[w][c];
        red[grp][c] = s;
        __syncthreads();
        if (tid < 64) mrow[tid] = (red[0][tid] + red[1][tid] + red[2][tid] + red[3][tid]) / 128.f;
        __syncthreads();
        const float m = mrow[c];
        float q = 0.f;
        for (int w = grp * 32; w < grp * 32 + 32; ++w) { const float d = hb[w][c] - m; q += d * d; }
        red[grp][c] = q;
        __syncthreads();
        if (tid < 64) {
            const float n2 = red[0][tid] + red[1][tid] + red[2][tid] + red[3][tid];
            const float n = fmaxf(sqrtf(n2), 1e-12f);
            const float m0 = mrow[tid];
            const float h0 = (hb[0][tid] - m0) / n, h1 = (hb[1][tid] - m0) / n;
            const float hN1 = (hb[127][tid] - m0) / n, hN2 = (hb[126][tid] - m0) / n;
            float* o = Sv + ((long long)b * 64 + tid) * 5;
            o[0] = -(hN2 + hN1); o[1] = -hN1; o[2] = 0.f; o[3] = -h0; o[4] = -(h0 + h1);
        }
    }
}

// merged: blocks [0,128) = flatnorm (wave-per-row), [128,256) = knorm
__global__ void norm_both(const float* __restrict__ kk, float* __restrict__ kn,
                          float* __restrict__ ab)
{
    if (blockIdx.x < 128) {
        const int wave = threadIdx.x >> 6, lane = threadIdx.x & 63;
        const int row = blockIdx.x * 4 + wave;
        const float* p = kk + (long long)row * 320;
        float n2 = 0.f;
        for (int d = lane; d < 320; d += 64) n2 += p[d] * p[d];
#pragma unroll
        for (int m = 1; m < 64; m <<= 1) n2 += __shfl_xor(n2, m, 64);
        const float n = fmaxf(sqrtf(n2), 1e-12f);
        float* o = ab + (long long)row * 320;
        for (int d = lane; d < 320; d += 64) o[d] = p[d] / n;
    } else {
        const int i = (blockIdx.x - 128) * NTHR + threadIdx.x;
        const float* p = kk + (long long)i * 5;
        float m = 0.f;
        for (int t = 0; t < 5; ++t) m += p[t];
        m *= 0.2f;
        float v[5]; float n2 = 0.f;
        for (int t = 0; t < 5; ++t) { v[t] = p[t] - m; n2 += v[t] * v[t]; }
        float n = fmaxf(sqrtf(n2), 1e-12f);
        for (int t = 0; t < 5; ++t) kn[(long long)i * 5 + t] = v[t] / n;
    }
}

// fused similarity + per-row log-softmax diag. grid (256, 3), block 256.
__global__ void simdot_nce(const float* __restrict__ kn, const float* __restrict__ Sv,
                           const float* __restrict__ ab, float* __restrict__ lp)
{
    const int j = threadIdx.x;
    const int i = blockIdx.x;
    const int z = blockIdx.y;
    const float* a;
    const float* b;
    float coef;
    if (z == 0)      { a = kn + (long long)i * 320;         b = Sv + (long long)(256 + j) * 320; coef = 10.f / 128.f; }
    else if (z == 1) { a = kn + (long long)(256 + i) * 320; b = Sv + (long long)j * 320;         coef = 10.f / 128.f; }
    else             { a = ab + (long long)i * 320;         b = ab + (long long)(256 + j) * 320; coef = 10.f; }
    float acc = 0.f;
    for (int d = 0; d < 320; ++d) acc += a[d] * b[d];
    const float v = acc * coef;

    __shared__ float red[NTHR];
    __shared__ float sdiag;
    if (j == i) sdiag = v;
    red[j] = v;
    __syncthreads();
    for (int off = NTHR / 2; off > 0; off >>= 1) {
        if (j < off) red[j] = fmaxf(red[j], red[j + off]);
        __syncthreads();
    }
    const float mx = red[0];
    __syncthreads();
    red[j] = expf(v - mx);
    __syncthreads();
    for (int off = NTHR / 2; off > 0; off >>= 1) {
        if (j < off) red[j] += red[j + off];
        __syncthreads();
    }
    if (j == 0) lp[z * 256 + i] = sdiag - (mx + logf(red[0]));
}

// reduce lp -> final loss scalar
__global__ void final3(const float* __restrict__ lp, float* __restrict__ out)
{
    __shared__ float red[NTHR];
    const int tid = threadIdx.x;
    float l[3];
    for (int z = 0; z < 3; ++z) {
        red[tid] = lp[z * 256 + tid];
        __syncthreads();
        for (int off = NTHR / 2; off > 0; off >>= 1) {
            if (tid < off) red[tid] += red[tid + off];
            __syncthreads();
        }
        l[z] = red[0];
        __syncthreads();
    }
    if (tid == 0)
        out[0] = 0.5f * (-l[0] / 256.f - l[1] / 256.f) + 0.5f * (-l[2] / 256.f);
}

// ---------------------------------------------------------------------------

extern "C" void kernel_launch(void* const* d_in, const int* in_sizes, int n_in,
                              void* d_out, int out_size, void* d_ws, size_t ws_size,
                              hipStream_t stream)
{
    const float* x1  = (const float*)d_in[0];
    const float* x2  = (const float*)d_in[1];
    const float* w1  = (const float*)d_in[2];
    const float* b1  = (const float*)d_in[3];
    const float* g1  = (const float*)d_in[4];
    const float* be1 = (const float*)d_in[5];
    const float* w2  = (const float*)d_in[6];
    const float* b2  = (const float*)d_in[7];
    const float* g2  = (const float*)d_in[8];
    const float* be2 = (const float*)d_in[9];
    const float* w3  = (const float*)d_in[10];
    const float* b3  = (const float*)d_in[11];
    const float* g3  = (const float*)d_in[12];
    const float* be3 = (const float*)d_in[13];
    const float* tw1 = (const float*)d_in[14];
    const float* tb1 = (const float*)d_in[15];
    const float* tg1 = (const float*)d_in[16];
    const float* tbe1= (const float*)d_in[17];
    const float* tw2 = (const float*)d_in[18];
    const float* tb2 = (const float*)d_in[19];
    const float* tg2 = (const float*)d_in[20];
    const float* tbe2= (const float*)d_in[21];
    float* out = (float*)d_out;

    char* ws = (char*)d_ws;
    size_t off = 0;
    auto alloc = [&](size_t bytes) -> void* {
        off = (off + 255) & ~(size_t)255;
        void* p = ws + off;
        off += bytes;
        return p;
    };
    typedef unsigned short u16;
    u16* xT2   = (u16*)alloc((size_t)BSZ2 * 2048 * 16 * 2);  // stage1 out   33.6MB
    u16* yMax2 = (u16*)alloc((size_t)BSZ2 * 512 * 32 * 2);   // 16.8MB
    u16* yMin2 = (u16*)alloc((size_t)BSZ2 * 512 * 32 * 2);   // 16.8MB
    u16* yMax3 = (u16*)alloc((size_t)BSZ2 * 128 * 64 * 2);   //  8.4MB
    u16* yMin3 = (u16*)alloc((size_t)BSZ2 * 128 * 64 * 2);   //  8.4MB
    u16* yT1   = (u16*)alloc((size_t)BSZ2 * 128 * 64 * 2);   //  8.4MB
    u16* yT2b  = (u16*)alloc((size_t)BSZ2 * 128 * 64 * 2);   //  8.4MB
    u16* wp1  = (u16*)alloc((size_t)512 * 2);
    u16* wp2  = (u16*)alloc((size_t)9 * 1 * 2 * 512 * 2);
    u16* wp3  = (u16*)alloc((size_t)17 * 1 * 4 * 512 * 2);
    u16* wpt1 = (u16*)alloc((size_t)5 * 2 * 4 * 512 * 2);
    u16* wpt2 = (u16*)alloc((size_t)3 * 2 * 4 * 512 * 2);
    float* kk   = (float*)alloc((size_t)BSZ2 * 320 * 4);
    float* kn   = (float*)alloc((size_t)BSZ2 * 320 * 4);
    float* ab   = (float*)alloc((size_t)BSZ2 * 320 * 4);
    float* Sv   = (float*)alloc((size_t)BSZ2 * 320 * 4);
    float* lp   = (float*)alloc((size_t)3 * 256 * 4);
    float* partials = (float*)alloc((size_t)16384 * 16 * 2 * 4);  // 2 MB
    float* scales = (float*)alloc((size_t)5 * 128 * 4);           // per-stage [2][C]
    float* shifts = (float*)alloc((size_t)5 * 128 * 4);
    float* sc1 = scales + 0 * 128, * sh1 = shifts + 0 * 128;
    float* sc2 = scales + 1 * 128, * sh2 = shifts + 1 * 128;
    float* sc3 = scales + 2 * 128, * sh3 = shifts + 2 * 128;
    float* sct1 = scales + 3 * 128, * sht1 = shifts + 3 * 128;
    float* sct2 = scales + 4 * 128, * sht2 = shifts + 4 * 128;

    build_all_wpacks<<<303, NTHR, 0, stream>>>(w1, w2, w3, tw1, tw2, wp1, wp2, wp3, wpt1, wpt2);

    // ---- stage 1: MFMA conv (1->16), stats -> finalize -> apply(pool) ----
    {
        const int nblk = BSZ2 * (8192 / 512);
        conv1_mfma<8, 0><<<nblk, 256, 0, stream>>>(x1, x2, wp1, b1, nullptr, nullptr, nullptr, partials);
        dim3 fg(16, 2);
        finalize2<16><<<fg, NTHR, 0, stream>>>(partials, nblk / 2, 1.f / ((float)256 * 8192), g1, be1, sc1, sh1);
        conv1_mfma<8, 1><<<nblk, 256, 0, stream>>>(x1, x2, wp1, b1, sc1, sh1, xT2, nullptr);
    }
    // ---- stage 2: conv + stats + pooled minmax ----
    {
        const int nblk = BSZ2 * (2048 / 256);
        conv_mfma2<16,32,17,8,2,9,1,2,4, 0,1><<<nblk, 256, 0, stream>>>(
            xT2, nullptr, nullptr, nullptr, wp2, b2, yMax2, yMin2, partials, 2048);
        dim3 fg(32, 2);
        finalize2<32><<<fg, NTHR, 0, stream>>>(partials, nblk / 2, 1.f / ((float)256 * 2048), g2, be2, sc2, sh2);
    }
    // ---- stage 3: stage-from-minmax(BN2) + conv + stats + pooled minmax ----
    {
        const int nblk = BSZ2 * (512 / 256);
        conv_mfma2<32,64,17,8,1,17,1,4,4, 1,1><<<nblk, 256, 0, stream>>>(
            yMax2, yMin2, sc2, sh2, wp3, b3, yMax3, yMin3, partials, 512);
        dim3 fg(64, 2);
        finalize2<64><<<fg, NTHR, 0, stream>>>(partials, nblk / 2, 1.f / ((float)256 * 512), g3, be3, sc3, sh3);
    }
    // ---- template stage 1: stage-from-minmax(BN3) + conv + stats + y ----
    {
        conv_mfma2<64,64,5,2,1,5,2,4,2, 1,0><<<BSZ2, 256, 0, stream>>>(
            yMax3, yMin3, sc3, sh3, wpt1, tb1, yT1, nullptr, partials, 128);
        dim3 fg(64, 2);
        finalize2<64><<<fg, NTHR, 0, stream>>>(partials, 256, 1.f / ((float)256 * 128), tg1, tbe1, sct1, sht1);
    }
    // ---- template stage 2: stage-from-y(BNt1) + conv + stats + y ----
    {
        conv_mfma2<64,64,3,1,1,3,2,4,2, 2,0><<<BSZ2, 256, 0, stream>>>(
            yT1, nullptr, sct1, sht1, wpt2, tb2, yT2b, nullptr, partials, 128);
        dim3 fg(64, 2);
        finalize2<64><<<fg, NTHR, 0, stream>>>(partials, 256, 1.f / ((float)256 * 128), tg2, tbe2, sct2, sht2);
    }

    // ---- tail: adapool(yT2b) + srow(minmax3), fused ----
    tail_pool_srow<<<2 * BSZ2, 256, 0, stream>>>(yT2b, sct2, sht2, yMax3, yMin3, sc3, sh3, kk, Sv);
    norm_both<<<256, NTHR, 0, stream>>>(kk, kn, ab);
    dim3 sg(256, 3);
    simdot_nce<<<sg, NTHR, 0, stream>>>(kn, Sv, ab, lp);
    final3<<<1, NTHR, 0, stream>>>(lp, out);
}

// Round 12
// 198.018 us; speedup vs baseline: 1.5193x; 1.0212x over previous
//
#include <hip/hip_runtime.h>
#include <hip/hip_bf16.h>
#include <math.h>

// ---------------------------------------------------------------------------
// TCCL model forward. Round 11:
//  - stage2 conv CHUNK 256->512 (ST=8): halve blocks, 2x MFMA per barrier
//  - knorm+flatnorm fused into tail adapool blocks (row is block-local);
//    norm_both kernel + kk buffer deleted
//  - simdot_nce dot loop vectorized float4 (320 -> 80 iters)
//  - rest identical to R10 (passing, absmax 0.0)
// ---------------------------------------------------------------------------

#define BSZ2 512          // combined batch (x1 ++ x2)
#define NTHR 256

typedef __attribute__((ext_vector_type(8))) short bf16x8;
typedef __attribute__((ext_vector_type(4))) float f32x4;

static inline int ceil_divll(long long a, int b) { return (int)((a + b - 1) / b); }

__device__ __forceinline__ unsigned short f2bf(float f) {
    unsigned u = __float_as_uint(f);
    u = (u + 0x7FFFu + ((u >> 16) & 1u)) >> 16;
    return (unsigned short)u;
}
__device__ __forceinline__ float bf2f(unsigned short h) {
    return __uint_as_float(((unsigned)h) << 16);
}
__device__ __forceinline__ float bflo(unsigned u) { return __uint_as_float(u << 16); }
__device__ __forceinline__ float bfhi(unsigned u) { return __uint_as_float(u & 0xFFFF0000u); }

// ---------------- stage 1 MFMA conv (Cin=1, K=17 padded to 32) --------------
// swapped operands: D[w][co], co = lane&15, w = kq*4+e (register axis pool)
// MODE 0 = stats partials; MODE 1 = BN+ReLU+maxpool4 -> bf16 [b][wp][16]
template<int WT, int MODE>
__global__ __launch_bounds__(256)
void conv1_mfma(const float* __restrict__ x1, const float* __restrict__ x2,
                const unsigned short* __restrict__ wpack1, const float* __restrict__ bias,
                const float* __restrict__ scale, const float* __restrict__ shift,
                unsigned short* __restrict__ out, float* __restrict__ partials)
{
    constexpr int W = 8192;
    constexpr int CHUNK = 4 * WT * 16;
    __shared__ float xs[CHUNK + 32];
    __shared__ float sred[(MODE == 0) ? 4 : 1][16];
    __shared__ float ssred[(MODE == 0) ? 4 : 1][16];

    const int tid = threadIdx.x;
    const int ntile = W / CHUNK;
    const int b = blockIdx.x / ntile;
    const int w0 = (blockIdx.x % ntile) * CHUNK;
    const float* xrow = (b < 256) ? x1 + (long long)b * W : x2 + (long long)(b - 256) * W;

    for (int i = tid; i < CHUNK + 32; i += 256) {
        const int gw = w0 - 8 + i;
        xs[i] = (gw >= 0 && gw < W) ? xrow[gw] : 0.f;
    }
    __syncthreads();

    const int lane = tid & 63, wave = tid >> 6;
    const int n = lane & 15, kq = lane >> 4;
    const bf16x8 a = *(const bf16x8*)(wpack1 + lane * 8);   // weights: co=n, k=kq*8+j

    f32x4 acc[WT];
#pragma unroll
    for (int wt = 0; wt < WT; ++wt) { acc[wt][0]=0.f; acc[wt][1]=0.f; acc[wt][2]=0.f; acc[wt][3]=0.f; }

    const int base0 = wave * WT * 16 + n + kq * 8;          // x frag: row w=n, k=kq*8+j
#pragma unroll
    for (int wt = 0; wt < WT; ++wt) {
        bf16x8 bv;
#pragma unroll
        for (int j = 0; j < 8; ++j) {
            __hip_bfloat16 h = __float2bfloat16(xs[base0 + wt * 16 + j]);
            bv[j] = *reinterpret_cast<short*>(&h);
        }
        acc[wt] = __builtin_amdgcn_mfma_f32_16x16x32_bf16(bv, a, acc[wt], 0, 0, 0);  // D[w][co]
    }

    if (MODE == 0) {
        const float bi = bias[n];
        float s_ = 0.f, ss_ = 0.f;
#pragma unroll
        for (int wt = 0; wt < WT; ++wt)
#pragma unroll
            for (int e = 0; e < 4; ++e) {
                const float y = acc[wt][e] + bi;
                s_ += y; ss_ += y * y;
            }
        s_  += __shfl_xor(s_, 16, 64);  s_  += __shfl_xor(s_, 32, 64);
        ss_ += __shfl_xor(ss_, 16, 64); ss_ += __shfl_xor(ss_, 32, 64);
        if (lane < 16) { sred[wave][n] = s_; ssred[wave][n] = ss_; }
        __syncthreads();
        if (tid < 16) {
            float sumv = 0.f, sumsq = 0.f;
#pragma unroll
            for (int wv = 0; wv < 4; ++wv) { sumv += sred[wv][tid]; sumsq += ssred[wv][tid]; }
            partials[((long long)blockIdx.x * 16 + tid) * 2 + 0] = sumv;
            partials[((long long)blockIdx.x * 16 + tid) * 2 + 1] = sumsq;
        }
    } else {
        const int half = b >> 8;
        const float bi = bias[n];
        const float scv = scale[half * 16 + n];
        const float shv = shift[half * 16 + n];
#pragma unroll
        for (int wt = 0; wt < WT; ++wt) {
            float v[4];
#pragma unroll
            for (int e = 0; e < 4; ++e) v[e] = fmaf(scv, acc[wt][e] + bi, shv);
            const float mx = fmaxf(fmaxf(fmaxf(v[0], v[1]), fmaxf(v[2], v[3])), 0.f);
            const int wp = (w0 >> 2) + wave * WT * 4 + wt * 4 + kq;
            out[((long long)b * 2048 + wp) * 16 + n] = f2bf(mx);
        }
    }
}

// per-channel, per-half finalize. grid (COUT, 2).
template<int COUT>
__global__ void finalize2(const float* __restrict__ partials, int nblk_half, float invN,
                          const float* __restrict__ g, const float* __restrict__ be,
                          float* __restrict__ scale, float* __restrict__ shift)
{
    const int co = blockIdx.x;
    const int half = blockIdx.y;
    const float* P = partials + (size_t)half * nblk_half * COUT * 2;
    float s = 0.f, ss = 0.f;
    for (int i = threadIdx.x; i < nblk_half; i += NTHR) {
        s  += P[((long long)i * COUT + co) * 2 + 0];
        ss += P[((long long)i * COUT + co) * 2 + 1];
    }
    __shared__ float red[NTHR][2];
    red[threadIdx.x][0] = s; red[threadIdx.x][1] = ss;
    __syncthreads();
    for (int off = NTHR / 2; off > 0; off >>= 1) {
        if ((int)threadIdx.x < off) {
            red[threadIdx.x][0] += red[threadIdx.x + off][0];
            red[threadIdx.x][1] += red[threadIdx.x + off][1];
        }
        __syncthreads();
    }
    if (threadIdx.x == 0) {
        const float m = red[0][0] * invN;
        const float v = red[0][1] * invN - m * m;
        const float inv = rsqrtf(v + 1e-5f);
        const float sc = g[co] * inv;
        scale[half * COUT + co] = sc;
        shift[half * COUT + co] = be[co] - sc * m;
    }
}

// ---------------- weight prepacks (one launch) ------------------------------
template<int CIN, int KK, int DT, int NP, int S, int CT>
__device__ __forceinline__ void pack_one(int idx, const float* __restrict__ wgt,
                                         unsigned short* __restrict__ wp)
{
    const int j = idx & 7;
    const int l = (idx >> 3) & 63;
    int rest = idx >> 9;
    const int ct = rest % CT; rest /= CT;
    const int s = rest % S;
    const int p = rest / S;
    const int co = ct * 16 + (l & 15);
    const int k = (l >> 4) * 8 + j;
    int ci, t;
    if (DT == 2) { ci = k & (CIN - 1); t = p * 2 + (k >> 4); }
    else         { ci = s * 32 + k;    t = p; }
    float v = (t < KK) ? wgt[((long long)co * CIN + ci) * KK + t] : 0.f;
    wp[idx] = f2bf(v);
}

__global__ void build_all_wpacks(const float* __restrict__ w1, const float* __restrict__ w2,
                                 const float* __restrict__ w3,
                                 const float* __restrict__ tw1, const float* __restrict__ tw2,
                                 unsigned short* __restrict__ wp1,
                                 unsigned short* __restrict__ wp2, unsigned short* __restrict__ wp3,
                                 unsigned short* __restrict__ wpt1, unsigned short* __restrict__ wpt2)
{
    const int idx = blockIdx.x * NTHR + threadIdx.x;
    const int n1 = 512;
    const int n2 = 9 * 1 * 2 * 512;
    const int n3 = 17 * 1 * 4 * 512;
    const int nt1 = 5 * 2 * 4 * 512;
    const int nt2 = 3 * 2 * 4 * 512;
    if (idx < n1) {
        const int j = idx & 7, l = idx >> 3;
        const int co = l & 15, k = (l >> 4) * 8 + j;
        wp1[idx] = f2bf((k < 17) ? w1[co * 17 + k] : 0.f);
    }
    else if (idx < n1 + n2) pack_one<16, 17, 2, 9, 1, 2>(idx - n1, w2, wp2);
    else if (idx < n1 + n2 + n3) pack_one<32, 17, 1, 17, 1, 4>(idx - n1 - n2, w3, wp3);
    else if (idx < n1 + n2 + n3 + nt1) pack_one<64, 5, 1, 5, 2, 4>(idx - n1 - n2 - n3, tw1, wpt1);
    else if (idx < n1 + n2 + n3 + nt1 + nt2) pack_one<64, 3, 1, 3, 2, 4>(idx - n1 - n2 - n3 - nt1, tw2, wpt2);
}

// ---------------- MFMA conv, generalized (swapped operands) -----------------
// D[w][co]: co = ct*16 + (lane&15), w = w0 + wave*ST*16 + st*16 + kq*4 + e
// SRCM: 0 = src bf16 as-is; 1 = (max,min) pair + prev BN select + relu;
//       2 = raw y + prev BN + relu
// OUTM: 0 = store raw y [b][W][COUT] + stats
//       1 = store pooled (max,min) of raw y [b][W/4][COUT] x2 + stats
template<int CIN, int COUT, int KK, int PAD, int DT, int NP, int S, int CT, int ST,
         int SRCM, int OUTM>
__global__ __launch_bounds__(256)
void conv_mfma2(const unsigned short* __restrict__ xA, const unsigned short* __restrict__ xB,
                const float* __restrict__ pscale, const float* __restrict__ pshift,
                const unsigned short* __restrict__ wpack, const float* __restrict__ bias,
                unsigned short* __restrict__ outA, unsigned short* __restrict__ outB,
                float* __restrict__ partials, int W)
{
    constexpr int CHUNK = 4 * ST * 16;
    constexpr int ROWB = CIN * 2 + 16;
    constexpr int ROWS = CHUNK + KK + (DT - 1) + 1;
    constexpr int DPR = CIN / 2;
    __shared__ __align__(16) unsigned char lx[ROWS * ROWB];
    __shared__ float sred[4][CT][16];
    __shared__ float ssred[4][CT][16];
    __shared__ float scb[(SRCM > 0) ? CIN : 1];
    __shared__ float shb[(SRCM > 0) ? CIN : 1];

    const int tid = threadIdx.x;
    const int ntile = W / CHUNK;
    const int b = blockIdx.x / ntile;
    const int tile = blockIdx.x % ntile;
    const int w0 = tile * CHUNK;

    if (SRCM > 0) {
        if (tid < CIN) {
            scb[tid] = pscale[(b >> 8) * CIN + tid];
            shb[tid] = pshift[(b >> 8) * CIN + tid];
        }
        __syncthreads();
    }

    for (int d = tid; d < ROWS * DPR; d += 256) {
        const int row = d / DPR;
        const int col = d % DPR;
        const int gw = w0 - PAD + row;
        unsigned v = 0;
        if (gw >= 0 && gw < W) {
            const long long src = ((long long)b * W + gw) * CIN + col * 2;
            if (SRCM == 0) {
                v = *(const unsigned*)(xA + src);
            } else {
                const unsigned va = *(const unsigned*)(xA + src);
                const float sc0 = scb[col * 2], sh0 = shb[col * 2];
                const float sc1 = scb[col * 2 + 1], sh1 = shb[col * 2 + 1];
                float f0, f1;
                if (SRCM == 1) {
                    const unsigned vb = *(const unsigned*)(xB + src);
                    f0 = fmaxf(fmaf(sc0, (sc0 > 0.f) ? bflo(va) : bflo(vb), sh0), 0.f);
                    f1 = fmaxf(fmaf(sc1, (sc1 > 0.f) ? bfhi(va) : bfhi(vb), sh1), 0.f);
                } else {
                    f0 = fmaxf(fmaf(sc0, bflo(va), sh0), 0.f);
                    f1 = fmaxf(fmaf(sc1, bfhi(va), sh1), 0.f);
                }
                v = (unsigned)f2bf(f0) | ((unsigned)f2bf(f1) << 16);
            }
        }
        *(unsigned*)(lx + row * ROWB + col * 4) = v;
    }
    __syncthreads();

    const int lane = tid & 63, wave = tid >> 6;
    const int n = lane & 15, kq = lane >> 4;
    int rowbase, cbyte;
    if (DT == 2) { rowbase = wave * ST * 16 + n + (kq >> 1); cbyte = (kq & 1) * 16; }
    else         { rowbase = wave * ST * 16 + n;             cbyte = kq * 16; }

    f32x4 acc[ST][CT];
#pragma unroll
    for (int st = 0; st < ST; ++st)
#pragma unroll
        for (int ct = 0; ct < CT; ++ct) { acc[st][ct][0]=0.f; acc[st][ct][1]=0.f; acc[st][ct][2]=0.f; acc[st][ct][3]=0.f; }

#pragma unroll
    for (int p = 0; p < NP; ++p) {
#pragma unroll
        for (int s = 0; s < S; ++s) {
            bf16x8 a[CT];
#pragma unroll
            for (int ct = 0; ct < CT; ++ct)
                a[ct] = *(const bf16x8*)(wpack + (((long long)(p * S + s) * CT + ct) * 64 + lane) * 8);
#pragma unroll
            for (int st = 0; st < ST; ++st) {
                const int r = rowbase + st * 16 + p * DT;
                const bf16x8 bf = *(const bf16x8*)(lx + r * ROWB + cbyte + s * 64);
#pragma unroll
                for (int ct = 0; ct < CT; ++ct)
                    acc[st][ct] = __builtin_amdgcn_mfma_f32_16x16x32_bf16(bf, a[ct], acc[st][ct], 0, 0, 0);
            }
        }
    }

    // epilogue: D[w][co] -> pool over register axis; per-lane scalar stores
    float s_[CT], ss_[CT];
#pragma unroll
    for (int ct = 0; ct < CT; ++ct) { s_[ct] = 0.f; ss_[ct] = 0.f; }

#pragma unroll
    for (int st = 0; st < ST; ++st) {
        const int wbase = w0 + wave * ST * 16 + st * 16 + kq * 4;
#pragma unroll
        for (int ct = 0; ct < CT; ++ct) {
            const float bi = bias[ct * 16 + n];
            float v[4];
#pragma unroll
            for (int e = 0; e < 4; ++e) {
                v[e] = acc[st][ct][e] + bi;
                s_[ct] += v[e];
                ss_[ct] += v[e] * v[e];
            }
            if (OUTM == 0) {
#pragma unroll
                for (int e = 0; e < 4; ++e)
                    outA[((long long)b * W + wbase + e) * COUT + ct * 16 + n] = f2bf(v[e]);
            } else {
                const float mx = fmaxf(fmaxf(v[0], v[1]), fmaxf(v[2], v[3]));
                const float mn = fminf(fminf(v[0], v[1]), fminf(v[2], v[3]));
                const long long o = ((long long)b * (W >> 2) + (wbase >> 2)) * COUT + ct * 16 + n;
                outA[o] = f2bf(mx);
                outB[o] = f2bf(mn);
            }
        }
    }
#pragma unroll
    for (int ct = 0; ct < CT; ++ct) {
        s_[ct]  += __shfl_xor(s_[ct], 16, 64);  s_[ct]  += __shfl_xor(s_[ct], 32, 64);
        ss_[ct] += __shfl_xor(ss_[ct], 16, 64); ss_[ct] += __shfl_xor(ss_[ct], 32, 64);
    }
    if (lane < 16) {
#pragma unroll
        for (int ct = 0; ct < CT; ++ct) { sred[wave][ct][n] = s_[ct]; ssred[wave][ct][n] = ss_[ct]; }
    }
    __syncthreads();
    if (tid < COUT) {
        const int ct = tid >> 4, nn = tid & 15;
        float sumv = 0.f, sumsq = 0.f;
#pragma unroll
        for (int wv = 0; wv < 4; ++wv) { sumv += sred[wv][ct][nn]; sumsq += ssred[wv][ct][nn]; }
        partials[((long long)blockIdx.x * COUT + tid) * 2 + 0] = sumv;
        partials[((long long)blockIdx.x * COUT + tid) * 2 + 1] = sumsq;
    }
}

// ---------------- fused tail --------------------------------------------------
// blocks [0,512): BN+ReLU+adapool5 from raw y_t2, then IN-BLOCK flatnorm (ab)
//                 and knorm (kn) — the 320-row is block-local.
// blocks [512,1024): h from stage3 minmax + BN select, center+norm -> Sv.
__global__ void tail_pool_srow(const unsigned short* __restrict__ yT2b,
                               const float* __restrict__ scT2, const float* __restrict__ shT2,
                               const unsigned short* __restrict__ yMax3,
                               const unsigned short* __restrict__ yMin3,
                               const float* __restrict__ scS3, const float* __restrict__ shS3,
                               float* __restrict__ kn, float* __restrict__ ab,
                               float* __restrict__ Sv)
{
    __shared__ float hb[128][64];
    const int tid = threadIdx.x;
    if (blockIdx.x < BSZ2) {
        const int b = blockIdx.x;
        __shared__ float pk[320];
        __shared__ float red2[NTHR];
        const uint2* yd = (const uint2*)(yT2b + (long long)b * 128 * 64);
        for (int i = tid; i < 128 * 16; i += 256) {
            const int w = i >> 4, c4 = (i & 15) * 4;
            const float* scp = scT2 + (b >> 8) * 64 + c4;
            const float* shp = shT2 + (b >> 8) * 64 + c4;
            const uint2 v = yd[i];
            hb[w][c4 + 0] = fmaxf(fmaf(scp[0], bflo(v.x), shp[0]), 0.f);
            hb[w][c4 + 1] = fmaxf(fmaf(scp[1], bfhi(v.x), shp[1]), 0.f);
            hb[w][c4 + 2] = fmaxf(fmaf(scp[2], bflo(v.y), shp[2]), 0.f);
            hb[w][c4 + 3] = fmaxf(fmaf(scp[3], bfhi(v.y), shp[3]), 0.f);
        }
        __syncthreads();
        const int bs[5] = {0, 25, 51, 76, 102};
        const int be[5] = {26, 52, 77, 103, 128};
        for (int o = tid; o < 320; o += 256) {
            const int cc = o & 63, bin = o >> 6;
            float acc = 0.f;
            for (int w = bs[bin]; w < be[bin]; ++w) acc += hb[w][cc];
            pk[cc * 5 + bin] = acc / (float)(be[bin] - bs[bin]);   // kk layout: c*5+bin
        }
        __syncthreads();
        // flatnorm over the 320 row
        float n2p = pk[tid] * pk[tid];
        if (tid < 64) n2p += pk[256 + tid] * pk[256 + tid];
        red2[tid] = n2p;
        __syncthreads();
        for (int off = NTHR / 2; off > 0; off >>= 1) {
            if (tid < off) red2[tid] += red2[tid + off];
            __syncthreads();
        }
        const float nrm = fmaxf(sqrtf(red2[0]), 1e-12f);
        for (int i = tid; i < 320; i += 256) ab[(long long)b * 320 + i] = pk[i] / nrm;
        // knorm per channel (center over 5 + l2)
        if (tid < 64) {
            const float* p = pk + tid * 5;
            float m = 0.f;
            for (int t = 0; t < 5; ++t) m += p[t];
            m *= 0.2f;
            float v[5]; float q = 0.f;
            for (int t = 0; t < 5; ++t) { v[t] = p[t] - m; q += v[t] * v[t]; }
            const float n = fmaxf(sqrtf(q), 1e-12f);
            float* o = kn + ((long long)b * 64 + tid) * 5;
            for (int t = 0; t < 5; ++t) o[t] = v[t] / n;
        }
    } else {
        __shared__ float red[4][64];
        __shared__ float mrow[64];
        const int b = blockIdx.x - BSZ2;
        const int c = tid & 63, grp = tid >> 6;
        const uint2* ya = (const uint2*)(yMax3 + (long long)b * 128 * 64);
        const uint2* yb = (const uint2*)(yMin3 + (long long)b * 128 * 64);
        for (int i = tid; i < 128 * 16; i += 256) {
            const int w = i >> 4, c4 = (i & 15) * 4;
            const float* scp = scS3 + (b >> 8) * 64 + c4;
            const float* shp = shS3 + (b >> 8) * 64 + c4;
            const uint2 va = ya[i], vb = yb[i];
            hb[w][c4 + 0] = fmaxf(fmaf(scp[0], (scp[0] > 0.f) ? bflo(va.x) : bflo(vb.x), shp[0]), 0.f);
            hb[w][c4 + 1] = fmaxf(fmaf(scp[1], (scp[1] > 0.f) ? bfhi(va.x) : bfhi(vb.x), shp[1]), 0.f);
            hb[w][c4 + 2] = fmaxf(fmaf(scp[2], (scp[2] > 0.f) ? bflo(va.y) : bflo(vb.y), shp[2]), 0.f);
            hb[w][c4 + 3] = fmaxf(fmaf(scp[3], (scp[3] > 0.f) ? bfhi(va.y) : bfhi(vb.y), shp[3]), 0.f);
        }
        __syncthreads();
        float s = 0.f;
        for (int w = grp * 32; w < grp * 32 + 32; ++w) s += hb[w][c];
        red[grp][c] = s;
        __syncthreads();
        if (tid < 64) mrow[tid] = (red[0][tid] + red[1][tid] + red[2][tid] + red[3][tid]) / 128.f;
        __syncthreads();
        const float m = mrow[c];
        float q = 0.f;
        for (int w = grp * 32; w < grp * 32 + 32; ++w) { const float d = hb[w][c] - m; q += d * d; }
        red[grp][c] = q;
        __syncthreads();
        if (tid < 64) {
            const float n2 = red[0][tid] + red[1][tid] + red[2][tid] + red[3][tid];
            const float n = fmaxf(sqrtf(n2), 1e-12f);
            const float m0 = mrow[tid];
            const float h0 = (hb[0][tid] - m0) / n, h1 = (hb[1][tid] - m0) / n;
            const float hN1 = (hb[127][tid] - m0) / n, hN2 = (hb[126][tid] - m0) / n;
            float* o = Sv + ((long long)b * 64 + tid) * 5;
            o[0] = -(hN2 + hN1); o[1] = -hN1; o[2] = 0.f; o[3] = -h0; o[4] = -(h0 + h1);
        }
    }
}

// fused similarity + per-row log-softmax diag. grid (256, 3), block 256.
__global__ void simdot_nce(const float* __restrict__ kn, const float* __restrict__ Sv,
                           const float* __restrict__ ab, float* __restrict__ lp)
{
    const int j = threadIdx.x;
    const int i = blockIdx.x;
    const int z = blockIdx.y;
    const float* a;
    const float* b;
    float coef;
    if (z == 0)      { a = kn + (long long)i * 320;         b = Sv + (long long)(256 + j) * 320; coef = 10.f / 128.f; }
    else if (z == 1) { a = kn + (long long)(256 + i) * 320; b = Sv + (long long)j * 320;         coef = 10.f / 128.f; }
    else             { a = ab + (long long)i * 320;         b = ab + (long long)(256 + j) * 320; coef = 10.f; }
    const float4* a4 = (const float4*)a;
    const float4* b4 = (const float4*)b;
    float acc = 0.f;
#pragma unroll 8
    for (int d = 0; d < 80; ++d) {
        const float4 xv = a4[d], yv = b4[d];
        acc += xv.x * yv.x + xv.y * yv.y + xv.z * yv.z + xv.w * yv.w;
    }
    const float v = acc * coef;

    __shared__ float red[NTHR];
    __shared__ float sdiag;
    if (j == i) sdiag = v;
    red[j] = v;
    __syncthreads();
    for (int off = NTHR / 2; off > 0; off >>= 1) {
        if (j < off) red[j] = fmaxf(red[j], red[j + off]);
        __syncthreads();
    }
    const float mx = red[0];
    __syncthreads();
    red[j] = expf(v - mx);
    __syncthreads();
    for (int off = NTHR / 2; off > 0; off >>= 1) {
        if (j < off) red[j] += red[j + off];
        __syncthreads();
    }
    if (j == 0) lp[z * 256 + i] = sdiag - (mx + logf(red[0]));
}

// reduce lp -> final loss scalar
__global__ void final3(const float* __restrict__ lp, float* __restrict__ out)
{
    __shared__ float red[NTHR];
    const int tid = threadIdx.x;
    float l[3];
    for (int z = 0; z < 3; ++z) {
        red[tid] = lp[z * 256 + tid];
        __syncthreads();
        for (int off = NTHR / 2; off > 0; off >>= 1) {
            if (tid < off) red[tid] += red[tid + off];
            __syncthreads();
        }
        l[z] = red[0];
        __syncthreads();
    }
    if (tid == 0)
        out[0] = 0.5f * (-l[0] / 256.f - l[1] / 256.f) + 0.5f * (-l[2] / 256.f);
}

// ---------------------------------------------------------------------------

extern "C" void kernel_launch(void* const* d_in, const int* in_sizes, int n_in,
                              void* d_out, int out_size, void* d_ws, size_t ws_size,
                              hipStream_t stream)
{
    const float* x1  = (const float*)d_in[0];
    const float* x2  = (const float*)d_in[1];
    const float* w1  = (const float*)d_in[2];
    const float* b1  = (const float*)d_in[3];
    const float* g1  = (const float*)d_in[4];
    const float* be1 = (const float*)d_in[5];
    const float* w2  = (const float*)d_in[6];
    const float* b2  = (const float*)d_in[7];
    const float* g2  = (const float*)d_in[8];
    const float* be2 = (const float*)d_in[9];
    const float* w3  = (const float*)d_in[10];
    const float* b3  = (const float*)d_in[11];
    const float* g3  = (const float*)d_in[12];
    const float* be3 = (const float*)d_in[13];
    const float* tw1 = (const float*)d_in[14];
    const float* tb1 = (const float*)d_in[15];
    const float* tg1 = (const float*)d_in[16];
    const float* tbe1= (const float*)d_in[17];
    const float* tw2 = (const float*)d_in[18];
    const float* tb2 = (const float*)d_in[19];
    const float* tg2 = (const float*)d_in[20];
    const float* tbe2= (const float*)d_in[21];
    float* out = (float*)d_out;

    char* ws = (char*)d_ws;
    size_t off = 0;
    auto alloc = [&](size_t bytes) -> void* {
        off = (off + 255) & ~(size_t)255;
        void* p = ws + off;
        off += bytes;
        return p;
    };
    typedef unsigned short u16;
    u16* xT2   = (u16*)alloc((size_t)BSZ2 * 2048 * 16 * 2);  // stage1 out   33.6MB
    u16* yMax2 = (u16*)alloc((size_t)BSZ2 * 512 * 32 * 2);   // 16.8MB
    u16* yMin2 = (u16*)alloc((size_t)BSZ2 * 512 * 32 * 2);   // 16.8MB
    u16* yMax3 = (u16*)alloc((size_t)BSZ2 * 128 * 64 * 2);   //  8.4MB
    u16* yMin3 = (u16*)alloc((size_t)BSZ2 * 128 * 64 * 2);   //  8.4MB
    u16* yT1   = (u16*)alloc((size_t)BSZ2 * 128 * 64 * 2);   //  8.4MB
    u16* yT2b  = (u16*)alloc((size_t)BSZ2 * 128 * 64 * 2);   //  8.4MB
    u16* wp1  = (u16*)alloc((size_t)512 * 2);
    u16* wp2  = (u16*)alloc((size_t)9 * 1 * 2 * 512 * 2);
    u16* wp3  = (u16*)alloc((size_t)17 * 1 * 4 * 512 * 2);
    u16* wpt1 = (u16*)alloc((size_t)5 * 2 * 4 * 512 * 2);
    u16* wpt2 = (u16*)alloc((size_t)3 * 2 * 4 * 512 * 2);
    float* kn   = (float*)alloc((size_t)BSZ2 * 320 * 4);
    float* ab   = (float*)alloc((size_t)BSZ2 * 320 * 4);
    float* Sv   = (float*)alloc((size_t)BSZ2 * 320 * 4);
    float* lp   = (float*)alloc((size_t)3 * 256 * 4);
    float* partials = (float*)alloc((size_t)16384 * 16 * 2 * 4);  // 2 MB
    float* scales = (float*)alloc((size_t)5 * 128 * 4);           // per-stage [2][C]
    float* shifts = (float*)alloc((size_t)5 * 128 * 4);
    float* sc1 = scales + 0 * 128, * sh1 = shifts + 0 * 128;
    float* sc2 = scales + 1 * 128, * sh2 = shifts + 1 * 128;
    float* sc3 = scales + 2 * 128, * sh3 = shifts + 2 * 128;
    float* sct1 = scales + 3 * 128, * sht1 = shifts + 3 * 128;
    float* sct2 = scales + 4 * 128, * sht2 = shifts + 4 * 128;

    build_all_wpacks<<<303, NTHR, 0, stream>>>(w1, w2, w3, tw1, tw2, wp1, wp2, wp3, wpt1, wpt2);

    // ---- stage 1: MFMA conv (1->16), stats -> finalize -> apply(pool) ----
    {
        const int nblk = BSZ2 * (8192 / 512);
        conv1_mfma<8, 0><<<nblk, 256, 0, stream>>>(x1, x2, wp1, b1, nullptr, nullptr, nullptr, partials);
        dim3 fg(16, 2);
        finalize2<16><<<fg, NTHR, 0, stream>>>(partials, nblk / 2, 1.f / ((float)256 * 8192), g1, be1, sc1, sh1);
        conv1_mfma<8, 1><<<nblk, 256, 0, stream>>>(x1, x2, wp1, b1, sc1, sh1, xT2, nullptr);
    }
    // ---- stage 2: conv + stats + pooled minmax (CHUNK=512) ----
    {
        const int nblk = BSZ2 * (2048 / 512);
        conv_mfma2<16,32,17,8,2,9,1,2,8, 0,1><<<nblk, 256, 0, stream>>>(
            xT2, nullptr, nullptr, nullptr, wp2, b2, yMax2, yMin2, partials, 2048);
        dim3 fg(32, 2);
        finalize2<32><<<fg, NTHR, 0, stream>>>(partials, nblk / 2, 1.f / ((float)256 * 2048), g2, be2, sc2, sh2);
    }
    // ---- stage 3: stage-from-minmax(BN2) + conv + stats + pooled minmax ----
    {
        const int nblk = BSZ2 * (512 / 256);
        conv_mfma2<32,64,17,8,1,17,1,4,4, 1,1><<<nblk, 256, 0, stream>>>(
            yMax2, yMin2, sc2, sh2, wp3, b3, yMax3, yMin3, partials, 512);
        dim3 fg(64, 2);
        finalize2<64><<<fg, NTHR, 0, stream>>>(partials, nblk / 2, 1.f / ((float)256 * 512), g3, be3, sc3, sh3);
    }
    // ---- template stage 1: stage-from-minmax(BN3) + conv + stats + y ----
    {
        conv_mfma2<64,64,5,2,1,5,2,4,2, 1,0><<<BSZ2, 256, 0, stream>>>(
            yMax3, yMin3, sc3, sh3, wpt1, tb1, yT1, nullptr, partials, 128);
        dim3 fg(64, 2);
        finalize2<64><<<fg, NTHR, 0, stream>>>(partials, 256, 1.f / ((float)256 * 128), tg1, tbe1, sct1, sht1);
    }
    // ---- template stage 2: stage-from-y(BNt1) + conv + stats + y ----
    {
        conv_mfma2<64,64,3,1,1,3,2,4,2, 2,0><<<BSZ2, 256, 0, stream>>>(
            yT1, nullptr, sct1, sht1, wpt2, tb2, yT2b, nullptr, partials, 128);
        dim3 fg(64, 2);
        finalize2<64><<<fg, NTHR, 0, stream>>>(partials, 256, 1.f / ((float)256 * 128), tg2, tbe2, sct2, sht2);
    }

    // ---- tail: adapool+norms (blocks 0..511) + srow (512..1023) ----
    tail_pool_srow<<<2 * BSZ2, 256, 0, stream>>>(yT2b, sct2, sht2, yMax3, yMin3, sc3, sh3, kn, ab, Sv);
    dim3 sg(256, 3);
    simdot_nce<<<sg, NTHR, 0, stream>>>(kn, Sv, ab, lp);
    final3<<<1, NTHR, 0, stream>>>(lp, out);
}